// Round 13
// baseline (497.141 us; speedup 1.0000x reference)
//
#include <hip/hip_runtime.h>
#include <math.h>

#define NN 50000
#define EE 800000
#define FIN 128
#define HID 96
#define NL 4
#define CHUNK 1024

typedef __attribute__((ext_vector_type(8))) short short8;
typedef __attribute__((ext_vector_type(4))) float floatx4;
typedef __attribute__((ext_vector_type(2))) _Float16 half2v;

#define WPREP_L (NL * 2 * 9216)       // 73728
#define WPREP_TOT (WPREP_L + 12288)   // 86016

struct u96 { unsigned x, y, z; };     // 12B payload (global_load_dwordx3)

__device__ __forceinline__ unsigned short f32_to_bf16_rne(float x) {
    unsigned u = __float_as_uint(x);
    unsigned r = (u + 0x7FFFu + ((u >> 16) & 1u)) >> 16;
    return (unsigned short)r;
}
__device__ __forceinline__ float bf16_to_f32(unsigned short h) {
    return __uint_as_float(((unsigned)h) << 16);
}

// ---------------- CSR build ----------------
__global__ void k_hist(const int* __restrict__ dst, int* __restrict__ deg, int E) {
    int e = blockIdx.x * blockDim.x + threadIdx.x;
    if (e < E) atomicAdd(&deg[dst[e]], 1);
}

__global__ void k_scan1(const int* __restrict__ deg, int* __restrict__ partials, int n) {
    __shared__ int lds[256];
    int t = threadIdx.x;
    int base = blockIdx.x * CHUNK + t * 4;
    int s = 0;
    #pragma unroll
    for (int q = 0; q < 4; q++) { int idx = base + q; if (idx < n) s += deg[idx]; }
    lds[t] = s; __syncthreads();
    for (int o = 128; o > 0; o >>= 1) { if (t < o) lds[t] += lds[t + o]; __syncthreads(); }
    if (t == 0) partials[blockIdx.x] = lds[0];
}

__global__ void k_scan_mid(int* partials, int nb, int* rowptr, int n) {
    int lane = threadIdx.x;
    int orig = (lane < nb) ? partials[lane] : 0;
    int v = orig;
    #pragma unroll
    for (int off = 1; off < 64; off <<= 1) {
        int u = __shfl_up(v, off);
        if (lane >= off) v += u;
    }
    if (lane < nb) partials[lane] = v - orig;
    if (lane == 63) rowptr[n] = v;
}

__global__ void k_scan3(const int* __restrict__ deg, const int* __restrict__ partials,
                        int* __restrict__ rowptr, int* __restrict__ cursor, int n) {
    __shared__ int lds[256];
    int t = threadIdx.x;
    int base = blockIdx.x * CHUNK + t * 4;
    int v[4];
    #pragma unroll
    for (int q = 0; q < 4; q++) { int idx = base + q; v[q] = (idx < n) ? deg[idx] : 0; }
    int tsum = v[0] + v[1] + v[2] + v[3];
    lds[t] = tsum; __syncthreads();
    for (int o = 1; o < 256; o <<= 1) {
        int add = (t >= o) ? lds[t - o] : 0;
        __syncthreads();
        lds[t] += add;
        __syncthreads();
    }
    int excl = lds[t] - tsum;
    int run = partials[blockIdx.x] + excl;
    #pragma unroll
    for (int q = 0; q < 4; q++) {
        int idx = base + q;
        if (idx < n) { rowptr[idx] = run; cursor[idx] = run; run += v[q]; }
    }
}

// packed payload: (fp16(ew) << 16) | src   (src < 65536)
__global__ void k_scatter(const int* __restrict__ src, const int* __restrict__ dst,
                          const float* __restrict__ ew, int* __restrict__ cursor,
                          unsigned* __restrict__ epack, int E) {
    int e = blockIdx.x * blockDim.x + threadIdx.x;
    if (e < E) {
        int p = atomicAdd(&cursor[dst[e]], 1);
        _Float16 hw = (_Float16)ew[e];
        unsigned short wb = *(unsigned short*)&hw;
        epack[p] = (unsigned)src[e] | ((unsigned)wb << 16);
    }
}

// ---------------- merged weight prep ----------------
__global__ void k_wprep_all(const float* __restrict__ Wl, const float* __restrict__ Wr,
                            const float* __restrict__ encW,
                            unsigned short* __restrict__ wf_hi, unsigned short* __restrict__ wf_lo,
                            unsigned short* __restrict__ we_hi, unsigned short* __restrict__ we_lo) {
    int t = blockIdx.x * blockDim.x + threadIdx.x;
    if (t < WPREP_L) {
        int within = t % 9216, pair = t / 9216;
        int lr = pair & 1, layer = pair >> 1;
        int j = within & 7;
        int lane = (within >> 3) & 63;
        int cs = within >> 9;
        int s = cs % 3, ct = cs / 3;
        int col = ct * 16 + (lane & 15);
        int k = s * 32 + (lane >> 4) * 8 + j;
        const float* W = (lr ? Wr : Wl) + (size_t)layer * HID * HID;
        float v = W[k * HID + col];
        unsigned short hi = f32_to_bf16_rne(v);
        wf_hi[t] = hi;
        wf_lo[t] = f32_to_bf16_rne(v - bf16_to_f32(hi));
    } else if (t < WPREP_TOT) {
        int u = t - WPREP_L;
        int j = u & 7;
        int lane = (u >> 3) & 63;
        int cs = u >> 9;
        int s = cs & 3, ct = cs >> 2;
        int col = ct * 16 + (lane & 15);
        int k = s * 32 + (lane >> 4) * 8 + j;
        float v = encW[k * HID + col];
        unsigned short hi = f32_to_bf16_rne(v);
        we_hi[u] = hi;
        we_lo[u] = f32_to_bf16_rne(v - bf16_to_f32(hi));
    }
}

// ---------------- encoder via split-bf16 MFMA + fused LN/relu/split epilogue ----------------
__global__ __launch_bounds__(256) void k_enc_mfma(const float* __restrict__ x,
        const unsigned short* __restrict__ we_hi, const unsigned short* __restrict__ we_lo,
        const float* __restrict__ b,
        const float* __restrict__ lng, const float* __restrict__ lnb,
        float* __restrict__ h,
        unsigned short* __restrict__ hn_hi, unsigned short* __restrict__ hn_lo, int n) {
    int t = threadIdx.x;
    int wave = t >> 6, lane = t & 63;
    int quad = lane >> 4, lid = lane & 15;
    int r0 = blockIdx.x * 64 + wave * 16;
    int arow = r0 + lid; if (arow >= n) arow = n - 1;
    short8 aH[4], aL[4];
    #pragma unroll
    for (int s = 0; s < 4; s++) {
        float4 p0 = *(const float4*)(x + (size_t)arow * FIN + s * 32 + quad * 8);
        float4 p1 = *(const float4*)(x + (size_t)arow * FIN + s * 32 + quad * 8 + 4);
        float f[8] = {p0.x, p0.y, p0.z, p0.w, p1.x, p1.y, p1.z, p1.w};
        #pragma unroll
        for (int j = 0; j < 8; j++) {
            unsigned short hi = f32_to_bf16_rne(f[j]);
            aH[s][j] = (short)hi;
            aL[s][j] = (short)f32_to_bf16_rne(f[j] - bf16_to_f32(hi));
        }
    }
    floatx4 o[6];
    #pragma unroll
    for (int ct = 0; ct < 6; ct++) {
        floatx4 acc = {0.f, 0.f, 0.f, 0.f};
        #pragma unroll
        for (int s = 0; s < 4; s++) {
            short8 bH = *(const short8*)(we_hi + ((ct * 4 + s) * 64 + lane) * 8);
            short8 bL = *(const short8*)(we_lo + ((ct * 4 + s) * 64 + lane) * 8);
            acc = __builtin_amdgcn_mfma_f32_16x16x32_bf16(aH[s], bH, acc, 0, 0, 0);
            acc = __builtin_amdgcn_mfma_f32_16x16x32_bf16(aH[s], bL, acc, 0, 0, 0);
            acc = __builtin_amdgcn_mfma_f32_16x16x32_bf16(aL[s], bH, acc, 0, 0, 0);
        }
        float bv = b[ct * 16 + lid];
        #pragma unroll
        for (int rg = 0; rg < 4; rg++) o[ct][rg] = acc[rg] + bv;
    }
    #pragma unroll
    for (int rg = 0; rg < 4; rg++) {
        float s1 = 0.f, s2 = 0.f;
        #pragma unroll
        for (int ct = 0; ct < 6; ct++) { s1 += o[ct][rg]; s2 += o[ct][rg] * o[ct][rg]; }
        #pragma unroll
        for (int off = 1; off < 16; off <<= 1) {
            s1 += __shfl_xor(s1, off);
            s2 += __shfl_xor(s2, off);
        }
        float mu = s1 * (1.f / 96.f);
        float var = s2 * (1.f / 96.f) - mu * mu;
        float rs = rsqrtf(var + 1e-5f);
        int orow = r0 + quad * 4 + rg;
        if (orow < n) {
            #pragma unroll
            for (int ct = 0; ct < 6; ct++) {
                int col = ct * 16 + lid;
                float v = o[ct][rg];
                h[(size_t)orow * HID + col] = v;
                float y = fmaxf((v - mu) * rs * lng[col] + lnb[col], 0.f);
                unsigned short hi = f32_to_bf16_rne(y);
                hn_hi[(size_t)orow * HID + col] = hi;
                hn_lo[(size_t)orow * HID + col] = f32_to_bf16_rne(y - bf16_to_f32(hi));
            }
        }
    }
}

// ---------------- layer GEMMs via split-bf16 MFMA (LDS-staged B, 32 rows/wave) ----------------
__global__ __launch_bounds__(256) void k_gemm2_mfma(
        const unsigned short* __restrict__ hn_hi, const unsigned short* __restrict__ hn_lo,
        const unsigned short* __restrict__ wf_hi, const unsigned short* __restrict__ wf_lo,
        const float* __restrict__ bl, const float* __restrict__ br,
        unsigned short* __restrict__ xl_h, unsigned short* __restrict__ xr_h, int n) {
    __shared__ unsigned short lh[9216];
    __shared__ unsigned short ll[9216];
    int t = threadIdx.x;
    int wave = t >> 6, lane = t & 63;
    int quad = lane >> 4, lid = lane & 15;
    int r0 = blockIdx.x * 128 + wave * 32;
    short8 aH[2][3], aL[2][3];
    #pragma unroll
    for (int hh = 0; hh < 2; hh++) {
        int arow = r0 + hh * 16 + lid; if (arow >= n) arow = n - 1;
        #pragma unroll
        for (int s = 0; s < 3; s++) {
            aH[hh][s] = *(const short8*)(hn_hi + (size_t)arow * HID + s * 32 + quad * 8);
            aL[hh][s] = *(const short8*)(hn_lo + (size_t)arow * HID + s * 32 + quad * 8);
        }
    }
    for (int lr = 0; lr < 2; lr++) {
        const unsigned short* sh = wf_hi + lr * 9216;
        const unsigned short* sl = wf_lo + lr * 9216;
        __syncthreads();
        for (int u = t; u < 1152; u += 256) {
            *(short8*)(lh + u * 8) = *(const short8*)(sh + u * 8);
            *(short8*)(ll + u * 8) = *(const short8*)(sl + u * 8);
        }
        __syncthreads();
        const float* bias = lr ? br : bl;
        unsigned short* out = lr ? xr_h : xl_h;
        #pragma unroll
        for (int ct = 0; ct < 6; ct++) {
            floatx4 acc0 = {0.f, 0.f, 0.f, 0.f};
            floatx4 acc1 = {0.f, 0.f, 0.f, 0.f};
            #pragma unroll
            for (int s = 0; s < 3; s++) {
                short8 bH = *(const short8*)(lh + ((ct * 3 + s) * 64 + lane) * 8);
                short8 bL = *(const short8*)(ll + ((ct * 3 + s) * 64 + lane) * 8);
                acc0 = __builtin_amdgcn_mfma_f32_16x16x32_bf16(aH[0][s], bH, acc0, 0, 0, 0);
                acc0 = __builtin_amdgcn_mfma_f32_16x16x32_bf16(aH[0][s], bL, acc0, 0, 0, 0);
                acc0 = __builtin_amdgcn_mfma_f32_16x16x32_bf16(aL[0][s], bH, acc0, 0, 0, 0);
                acc1 = __builtin_amdgcn_mfma_f32_16x16x32_bf16(aH[1][s], bH, acc1, 0, 0, 0);
                acc1 = __builtin_amdgcn_mfma_f32_16x16x32_bf16(aH[1][s], bL, acc1, 0, 0, 0);
                acc1 = __builtin_amdgcn_mfma_f32_16x16x32_bf16(aL[1][s], bH, acc1, 0, 0, 0);
            }
            int col = ct * 16 + lid;
            float bv = bias[col];
            #pragma unroll
            for (int rg = 0; rg < 4; rg++) {
                int orow0 = r0 + quad * 4 + rg;
                int orow1 = orow0 + 16;
                if (orow0 < n) {
                    _Float16 hv = (_Float16)(acc0[rg] + bv);
                    out[(size_t)orow0 * HID + col] = *(unsigned short*)&hv;
                }
                if (orow1 < n) {
                    _Float16 hv = (_Float16)(acc1[rg] + bv);
                    out[(size_t)orow1 * HID + col] = *(unsigned short*)&hv;
                }
            }
        }
    }
}

// ---------------- fused GATv2 + residual + next-layer LN (or final LN+fc) ----------------
// wave = 1 node; 4 groups x 16 lanes; each lane owns 6 dims (one dwordx3 per edge).
// Uniform-branch prefetch guards (beg/end wave-uniform) — no wasted clamp quads.
__global__ __launch_bounds__(256) void k_gat_fused(
        const unsigned short* __restrict__ xl_h, const unsigned short* __restrict__ xr_h,
        const unsigned* __restrict__ ep, const int* __restrict__ rowptr,
        const float* __restrict__ We, const float* __restrict__ att, const float* __restrict__ bias,
        float* __restrict__ h,
        unsigned short* __restrict__ hn_hi, unsigned short* __restrict__ hn_lo,
        float* __restrict__ out_final,
        const float* __restrict__ g, const float* __restrict__ bt,
        const float* __restrict__ fcW, const float* __restrict__ fcb,
        int mode, int n) {
    int lane = threadIdx.x & 63;
    int node = blockIdx.x * 4 + (threadIdx.x >> 6);
    if (node >= n) return;
    int grp = lane >> 4, sub = lane & 15;
    int d0 = sub * 6;
    unsigned gOffB = (unsigned)(sub * 12);

    const float LOG2E = 1.4426950408889634f;
    union U6 { u96 u; half2v h2[3]; _Float16 hf[6]; };
    half2v we_h[3], at_h[3], xr_hv[3];
    {
        U6 xrw;
        xrw.u = *(const u96*)((const char*)xr_h + ((unsigned)node * 192u + gOffB));
        float2 a0 = *(const float2*)(We + d0);
        float2 a1 = *(const float2*)(We + d0 + 2);
        float2 a2 = *(const float2*)(We + d0 + 4);
        float2 c0 = *(const float2*)(att + d0);
        float2 c1 = *(const float2*)(att + d0 + 2);
        float2 c2 = *(const float2*)(att + d0 + 4);
        we_h[0] = half2v{(_Float16)a0.x, (_Float16)a0.y};
        we_h[1] = half2v{(_Float16)a1.x, (_Float16)a1.y};
        we_h[2] = half2v{(_Float16)a2.x, (_Float16)a2.y};
        at_h[0] = half2v{(_Float16)(c0.x*LOG2E), (_Float16)(c0.y*LOG2E)};
        at_h[1] = half2v{(_Float16)(c1.x*LOG2E), (_Float16)(c1.y*LOG2E)};
        at_h[2] = half2v{(_Float16)(c2.x*LOG2E), (_Float16)(c2.y*LOG2E)};
        #pragma unroll
        for (int j = 0; j < 3; j++) xr_hv[j] = xrw.h2[j];
    }
    const half2v c02 = half2v{(_Float16)0.2f, (_Float16)0.2f};

    int beg = rowptr[node], end = rowptr[node + 1];
    float ssum = 0.f;
    float acc[6];
    #pragma unroll
    for (int j = 0; j < 6; j++) acc[j] = 0.f;

    auto lq = [&](int p, u96& vraw, _Float16& wh, bool& val) {
        int pe = p + grp;
        val = pe < end;
        int pc = val ? pe : end - 1;
        unsigned e = ep[pc];
        unsigned short wb = (unsigned short)(e >> 16);
        wh = *(_Float16*)&wb;
        vraw = *(const u96*)((const char*)xl_h + ((e & 0xFFFFu) * 192u + gOffB));
    };
    auto proc = [&](const u96& vraw, _Float16 wh, bool val) {
        U6 cv; cv.u = vraw;
        half2v w2 = half2v{wh, wh};
        float q = 0.f;
        #pragma unroll
        for (int j = 0; j < 3; j++) {
            half2v t = cv.h2[j] + xr_hv[j];
            t = w2 * we_h[j] + t;
            half2v t2 = t * c02;
            t = __builtin_elementwise_max(t, t2);
#if __has_builtin(__builtin_amdgcn_fdot2)
            q = __builtin_amdgcn_fdot2(t, at_h[j], q, false);
#else
            q = fmaf((float)t[0], (float)at_h[j][0], q);
            q = fmaf((float)t[1], (float)at_h[j][1], q);
#endif
        }
        q += __shfl_xor(q, 1); q += __shfl_xor(q, 2);
        q += __shfl_xor(q, 4); q += __shfl_xor(q, 8);
        float e = val ? exp2f(q) : 0.f;
        ssum += e;
        #pragma unroll
        for (int j = 0; j < 6; j++) acc[j] = fmaf((float)cv.hf[j], e, acc[j]);
    };

    if (beg < end) {
        u96 vA, vB; _Float16 wA, wB; bool okA, okB;
        lq(beg, vA, wA, okA);
        if (beg + 4 < end) lq(beg + 4, vB, wB, okB);   // uniform branch
        for (int p = beg; p < end; p += 8) {
            proc(vA, wA, okA);
            if (p + 8 < end) lq(p + 8, vA, wA, okA);   // uniform
            if (p + 4 < end) {                         // uniform
                proc(vB, wB, okB);
                if (p + 12 < end) lq(p + 12, vB, wB, okB);
            }
        }
    }

    ssum += __shfl_xor(ssum, 16); ssum += __shfl_xor(ssum, 32);
    #pragma unroll
    for (int j = 0; j < 6; j++) {
        acc[j] += __shfl_xor(acc[j], 16);
        acc[j] += __shfl_xor(acc[j], 32);
    }
    float inv = 1.f / (ssum + 1e-16f);

    float nh[6];
    float s1 = 0.f, s2 = 0.f;
    {
        float2 h0 = *(const float2*)(h + (size_t)node * HID + d0);
        float2 h1 = *(const float2*)(h + (size_t)node * HID + d0 + 2);
        float2 h2 = *(const float2*)(h + (size_t)node * HID + d0 + 4);
        float2 b0 = *(const float2*)(bias + d0);
        float2 b1 = *(const float2*)(bias + d0 + 2);
        float2 b2 = *(const float2*)(bias + d0 + 4);
        float hv[6] = {h0.x, h0.y, h1.x, h1.y, h2.x, h2.y};
        float bv[6] = {b0.x, b0.y, b1.x, b1.y, b2.x, b2.y};
        #pragma unroll
        for (int j = 0; j < 6; j++) {
            nh[j] = hv[j] + acc[j] * inv + bv[j];
            s1 += nh[j];
            s2 += nh[j] * nh[j];
        }
    }
    #pragma unroll
    for (int off = 1; off < 16; off <<= 1) {
        s1 += __shfl_xor(s1, off);
        s2 += __shfl_xor(s2, off);
    }
    float mu = s1 * (1.f / 96.f);
    float var = s2 * (1.f / 96.f) - mu * mu;
    float rs = rsqrtf(var + 1e-5f);

    if (mode == 0) {
        if (grp == 0) {
            float2 g0 = *(const float2*)(g + d0);
            float2 g1 = *(const float2*)(g + d0 + 2);
            float2 g2 = *(const float2*)(g + d0 + 4);
            float2 t0 = *(const float2*)(bt + d0);
            float2 t1 = *(const float2*)(bt + d0 + 2);
            float2 t2 = *(const float2*)(bt + d0 + 4);
            float gv[6] = {g0.x, g0.y, g1.x, g1.y, g2.x, g2.y};
            float tv[6] = {t0.x, t0.y, t1.x, t1.y, t2.x, t2.y};
            *(float2*)(h + (size_t)node * HID + d0)     = make_float2(nh[0], nh[1]);
            *(float2*)(h + (size_t)node * HID + d0 + 2) = make_float2(nh[2], nh[3]);
            *(float2*)(h + (size_t)node * HID + d0 + 4) = make_float2(nh[4], nh[5]);
            unsigned hi[3], lo[3];
            #pragma unroll
            for (int j = 0; j < 3; j++) {
                float ox = fmaxf((nh[2*j]   - mu) * rs * gv[2*j]   + tv[2*j],   0.f);
                float oy = fmaxf((nh[2*j+1] - mu) * rs * gv[2*j+1] + tv[2*j+1], 0.f);
                unsigned short hx = f32_to_bf16_rne(ox), hy = f32_to_bf16_rne(oy);
                unsigned short lx = f32_to_bf16_rne(ox - bf16_to_f32(hx));
                unsigned short ly = f32_to_bf16_rne(oy - bf16_to_f32(hy));
                hi[j] = (unsigned)hx | ((unsigned)hy << 16);
                lo[j] = (unsigned)lx | ((unsigned)ly << 16);
            }
            u96 wh = {hi[0], hi[1], hi[2]};
            u96 wl = {lo[0], lo[1], lo[2]};
            *(u96*)((char*)hn_hi + 2 * ((size_t)node * HID + d0)) = wh;
            *(u96*)((char*)hn_lo + 2 * ((size_t)node * HID + d0)) = wl;
        }
    } else {
        float pacc = 0.f;
        {
            float2 g0 = *(const float2*)(g + d0);
            float2 g1 = *(const float2*)(g + d0 + 2);
            float2 g2 = *(const float2*)(g + d0 + 4);
            float2 t0 = *(const float2*)(bt + d0);
            float2 t1 = *(const float2*)(bt + d0 + 2);
            float2 t2 = *(const float2*)(bt + d0 + 4);
            float2 w0 = *(const float2*)(fcW + d0);
            float2 w1 = *(const float2*)(fcW + d0 + 2);
            float2 w2 = *(const float2*)(fcW + d0 + 4);
            float gv[6] = {g0.x, g0.y, g1.x, g1.y, g2.x, g2.y};
            float tv[6] = {t0.x, t0.y, t1.x, t1.y, t2.x, t2.y};
            float wv[6] = {w0.x, w0.y, w1.x, w1.y, w2.x, w2.y};
            #pragma unroll
            for (int j = 0; j < 6; j++) {
                float y = fmaxf((nh[j] - mu) * rs * gv[j] + tv[j], 0.f);
                pacc = fmaf(y, wv[j], pacc);
            }
        }
        #pragma unroll
        for (int off = 1; off < 16; off <<= 1) pacc += __shfl_xor(pacc, off);
        if (lane == 0) out_final[node] = pacc + fcb[0];
    }
}

extern "C" void kernel_launch(void* const* d_in, const int* in_sizes, int n_in,
                              void* d_out, int out_size, void* d_ws, size_t ws_size,
                              hipStream_t stream) {
    const float* x    = (const float*)d_in[0];
    const int*   ei   = (const int*)  d_in[1];
    const float* ew   = (const float*)d_in[2];
    const float* encW = (const float*)d_in[3];
    const float* encB = (const float*)d_in[4];
    const float* Wl   = (const float*)d_in[5];
    const float* bl   = (const float*)d_in[6];
    const float* Wr   = (const float*)d_in[7];
    const float* br   = (const float*)d_in[8];
    const float* We   = (const float*)d_in[9];
    const float* att  = (const float*)d_in[10];
    const float* bias = (const float*)d_in[11];
    const float* lng  = (const float*)d_in[12];
    const float* lnb  = (const float*)d_in[13];
    const float* lnfg = (const float*)d_in[14];
    const float* lnfb = (const float*)d_in[15];
    const float* fcW  = (const float*)d_in[16];
    const float* fcb  = (const float*)d_in[17];
    float* out = (float*)d_out;

    const int* src = ei;
    const int* dst = ei + EE;

    char* ws = (char*)d_ws;
    size_t off = 0;
    auto alloc = [&](size_t bytes) -> void* {
        void* p = ws + off;
        off += (bytes + 255) & ~(size_t)255;
        return p;
    };
    float* h      = (float*)alloc((size_t)NN * HID * 4);
    unsigned short* xl_h  = (unsigned short*)alloc((size_t)NN * HID * 2 + 256);
    unsigned short* xr_h  = (unsigned short*)alloc((size_t)NN * HID * 2 + 256);
    unsigned short* hn_hi = (unsigned short*)alloc((size_t)NN * HID * 2);
    unsigned short* hn_lo = (unsigned short*)alloc((size_t)NN * HID * 2);
    unsigned short* wf_hi = (unsigned short*)alloc((size_t)WPREP_L * 2);
    unsigned short* wf_lo = (unsigned short*)alloc((size_t)WPREP_L * 2);
    unsigned short* we_hi = (unsigned short*)alloc(12288 * 2);
    unsigned short* we_lo = (unsigned short*)alloc(12288 * 2);
    int*   deg    = (int*)  alloc((size_t)NN * 4);
    int*   rowptr = (int*)  alloc((size_t)(NN + 1) * 4);
    int*   cursor = (int*)  alloc((size_t)NN * 4);
    unsigned* epack = (unsigned*)alloc((size_t)EE * 4);
    int*   parts  = (int*)  alloc(256 * 4);

    const int NB = (NN + CHUNK - 1) / CHUNK;   // 49
    const int EB = (EE + 255) / 256;           // 3125
    const int MB = (NN + 63) / 64;             // 782
    const int MB2 = (NN + 127) / 128;          // 391
    const int WB = (NN + 3) / 4;               // 12500

    // CSR build
    hipMemsetAsync(deg, 0, (size_t)NN * 4, stream);
    k_hist<<<EB, 256, 0, stream>>>(dst, deg, EE);
    k_scan1<<<NB, 256, 0, stream>>>(deg, parts, NN);
    k_scan_mid<<<1, 64, 0, stream>>>(parts, NB, rowptr, NN);
    k_scan3<<<NB, 256, 0, stream>>>(deg, parts, rowptr, cursor, NN);
    k_scatter<<<EB, 256, 0, stream>>>(src, dst, ew, cursor, epack, EE);

    // weight prep
    k_wprep_all<<<(WPREP_TOT + 255) / 256, 256, 0, stream>>>(Wl, Wr, encW, wf_hi, wf_lo, we_hi, we_lo);

    // encoder (+fused first LN)
    k_enc_mfma<<<MB, 256, 0, stream>>>(x, we_hi, we_lo, encB, lng, lnb, h, hn_hi, hn_lo, NN);

    for (int l = 0; l < NL; l++) {
        k_gemm2_mfma<<<MB2, 256, 0, stream>>>(hn_hi, hn_lo,
            wf_hi + (size_t)l * 2 * 9216, wf_lo + (size_t)l * 2 * 9216,
            bl + l * HID, br + l * HID, xl_h, xr_h, NN);
        if (l < NL - 1) {
            k_gat_fused<<<WB, 256, 0, stream>>>(xl_h, xr_h, epack, rowptr,
                We + l * HID, att + l * HID, bias + l * HID,
                h, hn_hi, hn_lo, (float*)nullptr,
                lng + (l + 1) * HID, lnb + (l + 1) * HID,
                (const float*)nullptr, (const float*)nullptr, 0, NN);
        } else {
            k_gat_fused<<<WB, 256, 0, stream>>>(xl_h, xr_h, epack, rowptr,
                We + l * HID, att + l * HID, bias + l * HID,
                h, (unsigned short*)nullptr, (unsigned short*)nullptr, out,
                lnfg, lnfb, fcW, fcb, 1, NN);
        }
    }
}

// Round 14
// 475.588 us; speedup vs baseline: 1.0453x; 1.0453x over previous
//
#include <hip/hip_runtime.h>
#include <math.h>

#define NN 50000
#define EE 800000
#define FIN 128
#define HID 96
#define NL 4
#define CHUNK 1024

typedef __attribute__((ext_vector_type(8))) short short8;
typedef __attribute__((ext_vector_type(4))) float floatx4;
typedef __attribute__((ext_vector_type(2))) _Float16 half2v;

#define WPREP_L (NL * 2 * 9216)       // 73728
#define WPREP_TOT (WPREP_L + 12288)   // 86016

struct u96 { unsigned x, y, z; };     // 12B payload (global_load_dwordx3)

__device__ __forceinline__ unsigned short f32_to_bf16_rne(float x) {
    unsigned u = __float_as_uint(x);
    unsigned r = (u + 0x7FFFu + ((u >> 16) & 1u)) >> 16;
    return (unsigned short)r;
}
__device__ __forceinline__ float bf16_to_f32(unsigned short h) {
    return __uint_as_float(((unsigned)h) << 16);
}

// ---------------- CSR build ----------------
__global__ void k_hist(const int* __restrict__ dst, int* __restrict__ deg, int E) {
    int e = blockIdx.x * blockDim.x + threadIdx.x;
    if (e < E) atomicAdd(&deg[dst[e]], 1);
}

__global__ void k_scan1(const int* __restrict__ deg, int* __restrict__ partials, int n) {
    __shared__ int lds[256];
    int t = threadIdx.x;
    int base = blockIdx.x * CHUNK + t * 4;
    int s = 0;
    #pragma unroll
    for (int q = 0; q < 4; q++) { int idx = base + q; if (idx < n) s += deg[idx]; }
    lds[t] = s; __syncthreads();
    for (int o = 128; o > 0; o >>= 1) { if (t < o) lds[t] += lds[t + o]; __syncthreads(); }
    if (t == 0) partials[blockIdx.x] = lds[0];
}

__global__ void k_scan_mid(int* partials, int nb, int* rowptr, int n) {
    int lane = threadIdx.x;
    int orig = (lane < nb) ? partials[lane] : 0;
    int v = orig;
    #pragma unroll
    for (int off = 1; off < 64; off <<= 1) {
        int u = __shfl_up(v, off);
        if (lane >= off) v += u;
    }
    if (lane < nb) partials[lane] = v - orig;
    if (lane == 63) rowptr[n] = v;
}

__global__ void k_scan3(const int* __restrict__ deg, const int* __restrict__ partials,
                        int* __restrict__ rowptr, int* __restrict__ cursor, int n) {
    __shared__ int lds[256];
    int t = threadIdx.x;
    int base = blockIdx.x * CHUNK + t * 4;
    int v[4];
    #pragma unroll
    for (int q = 0; q < 4; q++) { int idx = base + q; v[q] = (idx < n) ? deg[idx] : 0; }
    int tsum = v[0] + v[1] + v[2] + v[3];
    lds[t] = tsum; __syncthreads();
    for (int o = 1; o < 256; o <<= 1) {
        int add = (t >= o) ? lds[t - o] : 0;
        __syncthreads();
        lds[t] += add;
        __syncthreads();
    }
    int excl = lds[t] - tsum;
    int run = partials[blockIdx.x] + excl;
    #pragma unroll
    for (int q = 0; q < 4; q++) {
        int idx = base + q;
        if (idx < n) { rowptr[idx] = run; cursor[idx] = run; run += v[q]; }
    }
}

// packed payload: (fp16(ew) << 16) | src   (src < 65536)
__global__ void k_scatter(const int* __restrict__ src, const int* __restrict__ dst,
                          const float* __restrict__ ew, int* __restrict__ cursor,
                          unsigned* __restrict__ epack, int E) {
    int e = blockIdx.x * blockDim.x + threadIdx.x;
    if (e < E) {
        int p = atomicAdd(&cursor[dst[e]], 1);
        _Float16 hw = (_Float16)ew[e];
        unsigned short wb = *(unsigned short*)&hw;
        epack[p] = (unsigned)src[e] | ((unsigned)wb << 16);
    }
}

// ---------------- merged weight prep ----------------
__global__ void k_wprep_all(const float* __restrict__ Wl, const float* __restrict__ Wr,
                            const float* __restrict__ encW,
                            unsigned short* __restrict__ wf_hi, unsigned short* __restrict__ wf_lo,
                            unsigned short* __restrict__ we_hi, unsigned short* __restrict__ we_lo) {
    int t = blockIdx.x * blockDim.x + threadIdx.x;
    if (t < WPREP_L) {
        int within = t % 9216, pair = t / 9216;
        int lr = pair & 1, layer = pair >> 1;
        int j = within & 7;
        int lane = (within >> 3) & 63;
        int cs = within >> 9;
        int s = cs % 3, ct = cs / 3;
        int col = ct * 16 + (lane & 15);
        int k = s * 32 + (lane >> 4) * 8 + j;
        const float* W = (lr ? Wr : Wl) + (size_t)layer * HID * HID;
        float v = W[k * HID + col];
        unsigned short hi = f32_to_bf16_rne(v);
        wf_hi[t] = hi;
        wf_lo[t] = f32_to_bf16_rne(v - bf16_to_f32(hi));
    } else if (t < WPREP_TOT) {
        int u = t - WPREP_L;
        int j = u & 7;
        int lane = (u >> 3) & 63;
        int cs = u >> 9;
        int s = cs & 3, ct = cs >> 2;
        int col = ct * 16 + (lane & 15);
        int k = s * 32 + (lane >> 4) * 8 + j;
        float v = encW[k * HID + col];
        unsigned short hi = f32_to_bf16_rne(v);
        we_hi[u] = hi;
        we_lo[u] = f32_to_bf16_rne(v - bf16_to_f32(hi));
    }
}

// ---------------- encoder via split-bf16 MFMA + fused LN/relu/split epilogue ----------------
__global__ __launch_bounds__(256) void k_enc_mfma(const float* __restrict__ x,
        const unsigned short* __restrict__ we_hi, const unsigned short* __restrict__ we_lo,
        const float* __restrict__ b,
        const float* __restrict__ lng, const float* __restrict__ lnb,
        float* __restrict__ h,
        unsigned short* __restrict__ hn_hi, unsigned short* __restrict__ hn_lo, int n) {
    int t = threadIdx.x;
    int wave = t >> 6, lane = t & 63;
    int quad = lane >> 4, lid = lane & 15;
    int r0 = blockIdx.x * 64 + wave * 16;
    int arow = r0 + lid; if (arow >= n) arow = n - 1;
    short8 aH[4], aL[4];
    #pragma unroll
    for (int s = 0; s < 4; s++) {
        float4 p0 = *(const float4*)(x + (size_t)arow * FIN + s * 32 + quad * 8);
        float4 p1 = *(const float4*)(x + (size_t)arow * FIN + s * 32 + quad * 8 + 4);
        float f[8] = {p0.x, p0.y, p0.z, p0.w, p1.x, p1.y, p1.z, p1.w};
        #pragma unroll
        for (int j = 0; j < 8; j++) {
            unsigned short hi = f32_to_bf16_rne(f[j]);
            aH[s][j] = (short)hi;
            aL[s][j] = (short)f32_to_bf16_rne(f[j] - bf16_to_f32(hi));
        }
    }
    floatx4 o[6];
    #pragma unroll
    for (int ct = 0; ct < 6; ct++) {
        floatx4 acc = {0.f, 0.f, 0.f, 0.f};
        #pragma unroll
        for (int s = 0; s < 4; s++) {
            short8 bH = *(const short8*)(we_hi + ((ct * 4 + s) * 64 + lane) * 8);
            short8 bL = *(const short8*)(we_lo + ((ct * 4 + s) * 64 + lane) * 8);
            acc = __builtin_amdgcn_mfma_f32_16x16x32_bf16(aH[s], bH, acc, 0, 0, 0);
            acc = __builtin_amdgcn_mfma_f32_16x16x32_bf16(aH[s], bL, acc, 0, 0, 0);
            acc = __builtin_amdgcn_mfma_f32_16x16x32_bf16(aL[s], bH, acc, 0, 0, 0);
        }
        float bv = b[ct * 16 + lid];
        #pragma unroll
        for (int rg = 0; rg < 4; rg++) o[ct][rg] = acc[rg] + bv;
    }
    #pragma unroll
    for (int rg = 0; rg < 4; rg++) {
        float s1 = 0.f, s2 = 0.f;
        #pragma unroll
        for (int ct = 0; ct < 6; ct++) { s1 += o[ct][rg]; s2 += o[ct][rg] * o[ct][rg]; }
        #pragma unroll
        for (int off = 1; off < 16; off <<= 1) {
            s1 += __shfl_xor(s1, off);
            s2 += __shfl_xor(s2, off);
        }
        float mu = s1 * (1.f / 96.f);
        float var = s2 * (1.f / 96.f) - mu * mu;
        float rs = rsqrtf(var + 1e-5f);
        int orow = r0 + quad * 4 + rg;
        if (orow < n) {
            #pragma unroll
            for (int ct = 0; ct < 6; ct++) {
                int col = ct * 16 + lid;
                float v = o[ct][rg];
                h[(size_t)orow * HID + col] = v;
                float y = fmaxf((v - mu) * rs * lng[col] + lnb[col], 0.f);
                unsigned short hi = f32_to_bf16_rne(y);
                hn_hi[(size_t)orow * HID + col] = hi;
                hn_lo[(size_t)orow * HID + col] = f32_to_bf16_rne(y - bf16_to_f32(hi));
            }
        }
    }
}

// ---------------- layer GEMMs via split-bf16 MFMA (LDS-staged B, 16 rows/wave — R12 form) ----------------
__global__ __launch_bounds__(256) void k_gemm2_mfma(
        const unsigned short* __restrict__ hn_hi, const unsigned short* __restrict__ hn_lo,
        const unsigned short* __restrict__ wf_hi, const unsigned short* __restrict__ wf_lo,
        const float* __restrict__ bl, const float* __restrict__ br,
        unsigned short* __restrict__ xl_h, unsigned short* __restrict__ xr_h, int n) {
    __shared__ unsigned short lh[9216];
    __shared__ unsigned short ll[9216];
    int t = threadIdx.x;
    int wave = t >> 6, lane = t & 63;
    int quad = lane >> 4, lid = lane & 15;
    int r0 = blockIdx.x * 64 + wave * 16;
    int arow = r0 + lid; if (arow >= n) arow = n - 1;
    short8 aH[3], aL[3];
    #pragma unroll
    for (int s = 0; s < 3; s++) {
        aH[s] = *(const short8*)(hn_hi + (size_t)arow * HID + s * 32 + quad * 8);
        aL[s] = *(const short8*)(hn_lo + (size_t)arow * HID + s * 32 + quad * 8);
    }
    for (int lr = 0; lr < 2; lr++) {
        const unsigned short* sh = wf_hi + lr * 9216;
        const unsigned short* sl = wf_lo + lr * 9216;
        __syncthreads();
        for (int u = t; u < 1152; u += 256) {
            *(short8*)(lh + u * 8) = *(const short8*)(sh + u * 8);
            *(short8*)(ll + u * 8) = *(const short8*)(sl + u * 8);
        }
        __syncthreads();
        const float* bias = lr ? br : bl;
        unsigned short* out = lr ? xr_h : xl_h;
        #pragma unroll
        for (int ct = 0; ct < 6; ct++) {
            floatx4 acc = {0.f, 0.f, 0.f, 0.f};
            #pragma unroll
            for (int s = 0; s < 3; s++) {
                short8 bH = *(const short8*)(lh + ((ct * 3 + s) * 64 + lane) * 8);
                short8 bL = *(const short8*)(ll + ((ct * 3 + s) * 64 + lane) * 8);
                acc = __builtin_amdgcn_mfma_f32_16x16x32_bf16(aH[s], bH, acc, 0, 0, 0);
                acc = __builtin_amdgcn_mfma_f32_16x16x32_bf16(aH[s], bL, acc, 0, 0, 0);
                acc = __builtin_amdgcn_mfma_f32_16x16x32_bf16(aL[s], bH, acc, 0, 0, 0);
            }
            int col = ct * 16 + lid;
            float bv = bias[col];
            #pragma unroll
            for (int rg = 0; rg < 4; rg++) {
                int orow = r0 + quad * 4 + rg;
                if (orow < n) {
                    _Float16 hv = (_Float16)(acc[rg] + bv);
                    out[(size_t)orow * HID + col] = *(unsigned short*)&hv;
                }
            }
        }
    }
}

// ---------------- fused GATv2 + residual + next-layer LN (or final LN+fc) ----------------
// wave = 1 node; 4 groups x 16 lanes; each lane owns 6 dims (one dwordx3 per edge).
// R12 unguarded ping-pong loop (clamped loads), 4B packed edge payload.
__global__ __launch_bounds__(256) void k_gat_fused(
        const unsigned short* __restrict__ xl_h, const unsigned short* __restrict__ xr_h,
        const unsigned* __restrict__ ep, const int* __restrict__ rowptr,
        const float* __restrict__ We, const float* __restrict__ att, const float* __restrict__ bias,
        float* __restrict__ h,
        unsigned short* __restrict__ hn_hi, unsigned short* __restrict__ hn_lo,
        float* __restrict__ out_final,
        const float* __restrict__ g, const float* __restrict__ bt,
        const float* __restrict__ fcW, const float* __restrict__ fcb,
        int mode, int n) {
    int lane = threadIdx.x & 63;
    int node = blockIdx.x * 4 + (threadIdx.x >> 6);
    if (node >= n) return;
    int grp = lane >> 4, sub = lane & 15;
    int d0 = sub * 6;
    unsigned gOffB = (unsigned)(sub * 12);

    const float LOG2E = 1.4426950408889634f;
    union U6 { u96 u; half2v h2[3]; _Float16 hf[6]; };
    half2v we_h[3], at_h[3], xr_hv[3];
    {
        U6 xrw;
        xrw.u = *(const u96*)((const char*)xr_h + ((unsigned)node * 192u + gOffB));
        float2 a0 = *(const float2*)(We + d0);
        float2 a1 = *(const float2*)(We + d0 + 2);
        float2 a2 = *(const float2*)(We + d0 + 4);
        float2 c0 = *(const float2*)(att + d0);
        float2 c1 = *(const float2*)(att + d0 + 2);
        float2 c2 = *(const float2*)(att + d0 + 4);
        we_h[0] = half2v{(_Float16)a0.x, (_Float16)a0.y};
        we_h[1] = half2v{(_Float16)a1.x, (_Float16)a1.y};
        we_h[2] = half2v{(_Float16)a2.x, (_Float16)a2.y};
        at_h[0] = half2v{(_Float16)(c0.x*LOG2E), (_Float16)(c0.y*LOG2E)};
        at_h[1] = half2v{(_Float16)(c1.x*LOG2E), (_Float16)(c1.y*LOG2E)};
        at_h[2] = half2v{(_Float16)(c2.x*LOG2E), (_Float16)(c2.y*LOG2E)};
        #pragma unroll
        for (int j = 0; j < 3; j++) xr_hv[j] = xrw.h2[j];
    }
    const half2v c02 = half2v{(_Float16)0.2f, (_Float16)0.2f};

    int beg = rowptr[node], end = rowptr[node + 1];
    float ssum = 0.f;
    float acc[6];
    #pragma unroll
    for (int j = 0; j < 6; j++) acc[j] = 0.f;

    auto lq = [&](int p, u96& vraw, _Float16& wh, bool& val) {
        int pe = p + grp;
        val = pe < end;
        int pc = val ? pe : end - 1;
        unsigned e = ep[pc];
        unsigned short wb = (unsigned short)(e >> 16);
        wh = *(_Float16*)&wb;
        vraw = *(const u96*)((const char*)xl_h + ((e & 0xFFFFu) * 192u + gOffB));
    };
    auto proc = [&](const u96& vraw, _Float16 wh, bool val) {
        U6 cv; cv.u = vraw;
        half2v w2 = half2v{wh, wh};
        float q = 0.f;
        #pragma unroll
        for (int j = 0; j < 3; j++) {
            half2v t = cv.h2[j] + xr_hv[j];
            t = w2 * we_h[j] + t;
            half2v t2 = t * c02;
            t = __builtin_elementwise_max(t, t2);
#if __has_builtin(__builtin_amdgcn_fdot2)
            q = __builtin_amdgcn_fdot2(t, at_h[j], q, false);
#else
            q = fmaf((float)t[0], (float)at_h[j][0], q);
            q = fmaf((float)t[1], (float)at_h[j][1], q);
#endif
        }
        q += __shfl_xor(q, 1); q += __shfl_xor(q, 2);
        q += __shfl_xor(q, 4); q += __shfl_xor(q, 8);
        float e = val ? exp2f(q) : 0.f;
        ssum += e;
        #pragma unroll
        for (int j = 0; j < 6; j++) acc[j] = fmaf((float)cv.hf[j], e, acc[j]);
    };

    if (beg < end) {
        u96 vA, vB; _Float16 wA, wB; bool okA, okB;
        lq(beg,     vA, wA, okA);
        lq(beg + 4, vB, wB, okB);
        for (int p = beg; p < end; p += 8) {
            proc(vA, wA, okA);
            lq(p + 8, vA, wA, okA);
            proc(vB, wB, okB);
            lq(p + 12, vB, wB, okB);
        }
    }

    ssum += __shfl_xor(ssum, 16); ssum += __shfl_xor(ssum, 32);
    #pragma unroll
    for (int j = 0; j < 6; j++) {
        acc[j] += __shfl_xor(acc[j], 16);
        acc[j] += __shfl_xor(acc[j], 32);
    }
    float inv = 1.f / (ssum + 1e-16f);

    float nh[6];
    float s1 = 0.f, s2 = 0.f;
    {
        float2 h0 = *(const float2*)(h + (size_t)node * HID + d0);
        float2 h1 = *(const float2*)(h + (size_t)node * HID + d0 + 2);
        float2 h2 = *(const float2*)(h + (size_t)node * HID + d0 + 4);
        float2 b0 = *(const float2*)(bias + d0);
        float2 b1 = *(const float2*)(bias + d0 + 2);
        float2 b2 = *(const float2*)(bias + d0 + 4);
        float hv[6] = {h0.x, h0.y, h1.x, h1.y, h2.x, h2.y};
        float bv[6] = {b0.x, b0.y, b1.x, b1.y, b2.x, b2.y};
        #pragma unroll
        for (int j = 0; j < 6; j++) {
            nh[j] = hv[j] + acc[j] * inv + bv[j];
            s1 += nh[j];
            s2 += nh[j] * nh[j];
        }
    }
    #pragma unroll
    for (int off = 1; off < 16; off <<= 1) {
        s1 += __shfl_xor(s1, off);
        s2 += __shfl_xor(s2, off);
    }
    float mu = s1 * (1.f / 96.f);
    float var = s2 * (1.f / 96.f) - mu * mu;
    float rs = rsqrtf(var + 1e-5f);

    if (mode == 0) {
        if (grp == 0) {
            float2 g0 = *(const float2*)(g + d0);
            float2 g1 = *(const float2*)(g + d0 + 2);
            float2 g2 = *(const float2*)(g + d0 + 4);
            float2 t0 = *(const float2*)(bt + d0);
            float2 t1 = *(const float2*)(bt + d0 + 2);
            float2 t2 = *(const float2*)(bt + d0 + 4);
            float gv[6] = {g0.x, g0.y, g1.x, g1.y, g2.x, g2.y};
            float tv[6] = {t0.x, t0.y, t1.x, t1.y, t2.x, t2.y};
            *(float2*)(h + (size_t)node * HID + d0)     = make_float2(nh[0], nh[1]);
            *(float2*)(h + (size_t)node * HID + d0 + 2) = make_float2(nh[2], nh[3]);
            *(float2*)(h + (size_t)node * HID + d0 + 4) = make_float2(nh[4], nh[5]);
            unsigned hi[3], lo[3];
            #pragma unroll
            for (int j = 0; j < 3; j++) {
                float ox = fmaxf((nh[2*j]   - mu) * rs * gv[2*j]   + tv[2*j],   0.f);
                float oy = fmaxf((nh[2*j+1] - mu) * rs * gv[2*j+1] + tv[2*j+1], 0.f);
                unsigned short hx = f32_to_bf16_rne(ox), hy = f32_to_bf16_rne(oy);
                unsigned short lx = f32_to_bf16_rne(ox - bf16_to_f32(hx));
                unsigned short ly = f32_to_bf16_rne(oy - bf16_to_f32(hy));
                hi[j] = (unsigned)hx | ((unsigned)hy << 16);
                lo[j] = (unsigned)lx | ((unsigned)ly << 16);
            }
            u96 wh = {hi[0], hi[1], hi[2]};
            u96 wl = {lo[0], lo[1], lo[2]};
            *(u96*)((char*)hn_hi + 2 * ((size_t)node * HID + d0)) = wh;
            *(u96*)((char*)hn_lo + 2 * ((size_t)node * HID + d0)) = wl;
        }
    } else {
        float pacc = 0.f;
        {
            float2 g0 = *(const float2*)(g + d0);
            float2 g1 = *(const float2*)(g + d0 + 2);
            float2 g2 = *(const float2*)(g + d0 + 4);
            float2 t0 = *(const float2*)(bt + d0);
            float2 t1 = *(const float2*)(bt + d0 + 2);
            float2 t2 = *(const float2*)(bt + d0 + 4);
            float2 w0 = *(const float2*)(fcW + d0);
            float2 w1 = *(const float2*)(fcW + d0 + 2);
            float2 w2 = *(const float2*)(fcW + d0 + 4);
            float gv[6] = {g0.x, g0.y, g1.x, g1.y, g2.x, g2.y};
            float tv[6] = {t0.x, t0.y, t1.x, t1.y, t2.x, t2.y};
            float wv[6] = {w0.x, w0.y, w1.x, w1.y, w2.x, w2.y};
            #pragma unroll
            for (int j = 0; j < 6; j++) {
                float y = fmaxf((nh[j] - mu) * rs * gv[j] + tv[j], 0.f);
                pacc = fmaf(y, wv[j], pacc);
            }
        }
        #pragma unroll
        for (int off = 1; off < 16; off <<= 1) pacc += __shfl_xor(pacc, off);
        if (lane == 0) out_final[node] = pacc + fcb[0];
    }
}

extern "C" void kernel_launch(void* const* d_in, const int* in_sizes, int n_in,
                              void* d_out, int out_size, void* d_ws, size_t ws_size,
                              hipStream_t stream) {
    const float* x    = (const float*)d_in[0];
    const int*   ei   = (const int*)  d_in[1];
    const float* ew   = (const float*)d_in[2];
    const float* encW = (const float*)d_in[3];
    const float* encB = (const float*)d_in[4];
    const float* Wl   = (const float*)d_in[5];
    const float* bl   = (const float*)d_in[6];
    const float* Wr   = (const float*)d_in[7];
    const float* br   = (const float*)d_in[8];
    const float* We   = (const float*)d_in[9];
    const float* att  = (const float*)d_in[10];
    const float* bias = (const float*)d_in[11];
    const float* lng  = (const float*)d_in[12];
    const float* lnb  = (const float*)d_in[13];
    const float* lnfg = (const float*)d_in[14];
    const float* lnfb = (const float*)d_in[15];
    const float* fcW  = (const float*)d_in[16];
    const float* fcb  = (const float*)d_in[17];
    float* out = (float*)d_out;

    const int* src = ei;
    const int* dst = ei + EE;

    char* ws = (char*)d_ws;
    size_t off = 0;
    auto alloc = [&](size_t bytes) -> void* {
        void* p = ws + off;
        off += (bytes + 255) & ~(size_t)255;
        return p;
    };
    float* h      = (float*)alloc((size_t)NN * HID * 4);
    unsigned short* xl_h  = (unsigned short*)alloc((size_t)NN * HID * 2 + 256);
    unsigned short* xr_h  = (unsigned short*)alloc((size_t)NN * HID * 2 + 256);
    unsigned short* hn_hi = (unsigned short*)alloc((size_t)NN * HID * 2);
    unsigned short* hn_lo = (unsigned short*)alloc((size_t)NN * HID * 2);
    unsigned short* wf_hi = (unsigned short*)alloc((size_t)WPREP_L * 2);
    unsigned short* wf_lo = (unsigned short*)alloc((size_t)WPREP_L * 2);
    unsigned short* we_hi = (unsigned short*)alloc(12288 * 2);
    unsigned short* we_lo = (unsigned short*)alloc(12288 * 2);
    int*   deg    = (int*)  alloc((size_t)NN * 4);
    int*   rowptr = (int*)  alloc((size_t)(NN + 1) * 4);
    int*   cursor = (int*)  alloc((size_t)NN * 4);
    unsigned* epack = (unsigned*)alloc((size_t)EE * 4);
    int*   parts  = (int*)  alloc(256 * 4);

    const int NB = (NN + CHUNK - 1) / CHUNK;   // 49
    const int EB = (EE + 255) / 256;           // 3125
    const int MB = (NN + 63) / 64;             // 782
    const int WB = (NN + 3) / 4;               // 12500

    // CSR build
    hipMemsetAsync(deg, 0, (size_t)NN * 4, stream);
    k_hist<<<EB, 256, 0, stream>>>(dst, deg, EE);
    k_scan1<<<NB, 256, 0, stream>>>(deg, parts, NN);
    k_scan_mid<<<1, 64, 0, stream>>>(parts, NB, rowptr, NN);
    k_scan3<<<NB, 256, 0, stream>>>(deg, parts, rowptr, cursor, NN);
    k_scatter<<<EB, 256, 0, stream>>>(src, dst, ew, cursor, epack, EE);

    // weight prep
    k_wprep_all<<<(WPREP_TOT + 255) / 256, 256, 0, stream>>>(Wl, Wr, encW, wf_hi, wf_lo, we_hi, we_lo);

    // encoder (+fused first LN)
    k_enc_mfma<<<MB, 256, 0, stream>>>(x, we_hi, we_lo, encB, lng, lnb, h, hn_hi, hn_lo, NN);

    for (int l = 0; l < NL; l++) {
        k_gemm2_mfma<<<MB, 256, 0, stream>>>(hn_hi, hn_lo,
            wf_hi + (size_t)l * 2 * 9216, wf_lo + (size_t)l * 2 * 9216,
            bl + l * HID, br + l * HID, xl_h, xr_h, NN);
        if (l < NL - 1) {
            k_gat_fused<<<WB, 256, 0, stream>>>(xl_h, xr_h, epack, rowptr,
                We + l * HID, att + l * HID, bias + l * HID,
                h, hn_hi, hn_lo, (float*)nullptr,
                lng + (l + 1) * HID, lnb + (l + 1) * HID,
                (const float*)nullptr, (const float*)nullptr, 0, NN);
        } else {
            k_gat_fused<<<WB, 256, 0, stream>>>(xl_h, xr_h, epack, rowptr,
                We + l * HID, att + l * HID, bias + l * HID,
                h, (unsigned short*)nullptr, (unsigned short*)nullptr, out,
                lnfg, lnfb, fcW, fcb, 1, NN);
        }
    }
}

// Round 15
// 451.284 us; speedup vs baseline: 1.1016x; 1.0539x over previous
//
#include <hip/hip_runtime.h>
#include <math.h>

#define NN 50000
#define EE 800000
#define FIN 128
#define HID 96
#define NL 4
#define CHUNK 1024

typedef __attribute__((ext_vector_type(8))) short short8;
typedef __attribute__((ext_vector_type(4))) float floatx4;
typedef __attribute__((ext_vector_type(2))) _Float16 half2v;

#define WPREP_L (NL * 2 * 9216)       // 73728
#define WPREP_TOT (WPREP_L + 12288)   // 86016

#define PH1E 4096
#define NBUCK 98                       // dst>>9 buckets (512 nodes each)
#define BCAP 9216                      // mean 8192 + ~11 sigma

struct u96 { unsigned x, y, z; };     // 12B payload (global_load_dwordx3)

__device__ __forceinline__ unsigned short f32_to_bf16_rne(float x) {
    unsigned u = __float_as_uint(x);
    unsigned r = (u + 0x7FFFu + ((u >> 16) & 1u)) >> 16;
    return (unsigned short)r;
}
__device__ __forceinline__ float bf16_to_f32(unsigned short h) {
    return __uint_as_float(((unsigned)h) << 16);
}

// ---------------- CSR build ----------------
__global__ void k_hist(const int* __restrict__ dst, int* __restrict__ deg, int E) {
    int e = blockIdx.x * blockDim.x + threadIdx.x;
    if (e < E) atomicAdd(&deg[dst[e]], 1);
}

__global__ void k_scan1(const int* __restrict__ deg, int* __restrict__ partials, int n) {
    __shared__ int lds[256];
    int t = threadIdx.x;
    int base = blockIdx.x * CHUNK + t * 4;
    int s = 0;
    #pragma unroll
    for (int q = 0; q < 4; q++) { int idx = base + q; if (idx < n) s += deg[idx]; }
    lds[t] = s; __syncthreads();
    for (int o = 128; o > 0; o >>= 1) { if (t < o) lds[t] += lds[t + o]; __syncthreads(); }
    if (t == 0) partials[blockIdx.x] = lds[0];
}

__global__ void k_scan_mid(int* partials, int nb, int* rowptr, int n) {
    int lane = threadIdx.x;
    int orig = (lane < nb) ? partials[lane] : 0;
    int v = orig;
    #pragma unroll
    for (int off = 1; off < 64; off <<= 1) {
        int u = __shfl_up(v, off);
        if (lane >= off) v += u;
    }
    if (lane < nb) partials[lane] = v - orig;
    if (lane == 63) rowptr[n] = v;
}

__global__ void k_scan3(const int* __restrict__ deg, const int* __restrict__ partials,
                        int* __restrict__ rowptr, int* __restrict__ cursor, int n) {
    __shared__ int lds[256];
    int t = threadIdx.x;
    int base = blockIdx.x * CHUNK + t * 4;
    int v[4];
    #pragma unroll
    for (int q = 0; q < 4; q++) { int idx = base + q; v[q] = (idx < n) ? deg[idx] : 0; }
    int tsum = v[0] + v[1] + v[2] + v[3];
    lds[t] = tsum; __syncthreads();
    for (int o = 1; o < 256; o <<= 1) {
        int add = (t >= o) ? lds[t - o] : 0;
        __syncthreads();
        lds[t] += add;
        __syncthreads();
    }
    int excl = lds[t] - tsum;
    int run = partials[blockIdx.x] + excl;
    #pragma unroll
    for (int q = 0; q < 4; q++) {
        int idx = base + q;
        if (idx < n) { rowptr[idx] = run; cursor[idx] = run; run += v[q]; }
    }
}

// ---------------- two-phase binned scatter (kills 64B-line write amplification) ----------------
// phase 1: LDS counting-sort 4096 edges by bucket (dst>>9), append segments to ibuf
__global__ __launch_bounds__(256) void k_binscatter(const int* __restrict__ src,
        const int* __restrict__ dst, const float* __restrict__ ew,
        int* __restrict__ gcur, uint2* __restrict__ ibuf, int E) {
    __shared__ uint2 st[PH1E];
    __shared__ int cnt[NBUCK], off[NBUCK], cur[NBUCK], gbase[NBUCK];
    int t = threadIdx.x;
    int e0 = blockIdx.x * PH1E;
    for (int i = t; i < NBUCK; i += 256) { cnt[i] = 0; cur[i] = 0; }
    __syncthreads();
    #pragma unroll
    for (int k = 0; k < PH1E / 256; k++) {
        int e = e0 + k * 256 + t;
        if (e < E) atomicAdd(&cnt[dst[e] >> 9], 1);
    }
    __syncthreads();
    if (t == 0) {
        int run = 0;
        for (int b = 0; b < NBUCK; b++) { off[b] = run; run += cnt[b]; }
    }
    __syncthreads();
    #pragma unroll
    for (int k = 0; k < PH1E / 256; k++) {
        int e = e0 + k * 256 + t;
        if (e < E) {
            int d = dst[e];
            int b = d >> 9;
            int p = off[b] + atomicAdd(&cur[b], 1);
            _Float16 hw = (_Float16)ew[e];
            unsigned short wb = *(unsigned short*)&hw;
            st[p] = make_uint2((unsigned)d, (unsigned)src[e] | ((unsigned)wb << 16));
        }
    }
    __syncthreads();
    if (t < NBUCK) gbase[t] = atomicAdd(&gcur[t], cur[t]);
    __syncthreads();
    int total = min(PH1E, E - e0);
    for (int i = t; i < total; i += 256) {
        uint2 v = st[i];
        int b = v.x >> 9;
        ibuf[(size_t)b * BCAP + gbase[b] + (i - off[b])] = v;
    }
}

// phase 2: one block per bucket; final CSR placement, writes confined to one 32KB region/XCD
__global__ __launch_bounds__(256) void k_binplace(const uint2* __restrict__ ibuf,
        const int* __restrict__ gcur, const int* __restrict__ rowptr,
        unsigned* __restrict__ epack, int n) {
    __shared__ int cur[512];
    int t = threadIdx.x;
    int b = blockIdx.x;
    int n0 = b << 9;
    for (int i = t; i < 512; i += 256) {
        int node = n0 + i;
        cur[i] = (node < n) ? rowptr[node] : 0;
    }
    __syncthreads();
    int nb = gcur[b];
    for (int i = t; i < nb; i += 256) {
        uint2 v = ibuf[(size_t)b * BCAP + i];
        int p = atomicAdd(&cur[(int)v.x - n0], 1);
        epack[p] = v.y;
    }
}

// ---------------- merged weight prep ----------------
__global__ void k_wprep_all(const float* __restrict__ Wl, const float* __restrict__ Wr,
                            const float* __restrict__ encW,
                            unsigned short* __restrict__ wf_hi, unsigned short* __restrict__ wf_lo,
                            unsigned short* __restrict__ we_hi, unsigned short* __restrict__ we_lo) {
    int t = blockIdx.x * blockDim.x + threadIdx.x;
    if (t < WPREP_L) {
        int within = t % 9216, pair = t / 9216;
        int lr = pair & 1, layer = pair >> 1;
        int j = within & 7;
        int lane = (within >> 3) & 63;
        int cs = within >> 9;
        int s = cs % 3, ct = cs / 3;
        int col = ct * 16 + (lane & 15);
        int k = s * 32 + (lane >> 4) * 8 + j;
        const float* W = (lr ? Wr : Wl) + (size_t)layer * HID * HID;
        float v = W[k * HID + col];
        unsigned short hi = f32_to_bf16_rne(v);
        wf_hi[t] = hi;
        wf_lo[t] = f32_to_bf16_rne(v - bf16_to_f32(hi));
    } else if (t < WPREP_TOT) {
        int u = t - WPREP_L;
        int j = u & 7;
        int lane = (u >> 3) & 63;
        int cs = u >> 9;
        int s = cs & 3, ct = cs >> 2;
        int col = ct * 16 + (lane & 15);
        int k = s * 32 + (lane >> 4) * 8 + j;
        float v = encW[k * HID + col];
        unsigned short hi = f32_to_bf16_rne(v);
        we_hi[u] = hi;
        we_lo[u] = f32_to_bf16_rne(v - bf16_to_f32(hi));
    }
}

// ---------------- encoder via split-bf16 MFMA + fused LN/relu/split epilogue ----------------
__global__ __launch_bounds__(256) void k_enc_mfma(const float* __restrict__ x,
        const unsigned short* __restrict__ we_hi, const unsigned short* __restrict__ we_lo,
        const float* __restrict__ b,
        const float* __restrict__ lng, const float* __restrict__ lnb,
        float* __restrict__ h,
        unsigned short* __restrict__ hn_hi, unsigned short* __restrict__ hn_lo, int n) {
    int t = threadIdx.x;
    int wave = t >> 6, lane = t & 63;
    int quad = lane >> 4, lid = lane & 15;
    int r0 = blockIdx.x * 64 + wave * 16;
    int arow = r0 + lid; if (arow >= n) arow = n - 1;
    short8 aH[4], aL[4];
    #pragma unroll
    for (int s = 0; s < 4; s++) {
        float4 p0 = *(const float4*)(x + (size_t)arow * FIN + s * 32 + quad * 8);
        float4 p1 = *(const float4*)(x + (size_t)arow * FIN + s * 32 + quad * 8 + 4);
        float f[8] = {p0.x, p0.y, p0.z, p0.w, p1.x, p1.y, p1.z, p1.w};
        #pragma unroll
        for (int j = 0; j < 8; j++) {
            unsigned short hi = f32_to_bf16_rne(f[j]);
            aH[s][j] = (short)hi;
            aL[s][j] = (short)f32_to_bf16_rne(f[j] - bf16_to_f32(hi));
        }
    }
    floatx4 o[6];
    #pragma unroll
    for (int ct = 0; ct < 6; ct++) {
        floatx4 acc = {0.f, 0.f, 0.f, 0.f};
        #pragma unroll
        for (int s = 0; s < 4; s++) {
            short8 bH = *(const short8*)(we_hi + ((ct * 4 + s) * 64 + lane) * 8);
            short8 bL = *(const short8*)(we_lo + ((ct * 4 + s) * 64 + lane) * 8);
            acc = __builtin_amdgcn_mfma_f32_16x16x32_bf16(aH[s], bH, acc, 0, 0, 0);
            acc = __builtin_amdgcn_mfma_f32_16x16x32_bf16(aH[s], bL, acc, 0, 0, 0);
            acc = __builtin_amdgcn_mfma_f32_16x16x32_bf16(aL[s], bH, acc, 0, 0, 0);
        }
        float bv = b[ct * 16 + lid];
        #pragma unroll
        for (int rg = 0; rg < 4; rg++) o[ct][rg] = acc[rg] + bv;
    }
    #pragma unroll
    for (int rg = 0; rg < 4; rg++) {
        float s1 = 0.f, s2 = 0.f;
        #pragma unroll
        for (int ct = 0; ct < 6; ct++) { s1 += o[ct][rg]; s2 += o[ct][rg] * o[ct][rg]; }
        #pragma unroll
        for (int off = 1; off < 16; off <<= 1) {
            s1 += __shfl_xor(s1, off);
            s2 += __shfl_xor(s2, off);
        }
        float mu = s1 * (1.f / 96.f);
        float var = s2 * (1.f / 96.f) - mu * mu;
        float rs = rsqrtf(var + 1e-5f);
        int orow = r0 + quad * 4 + rg;
        if (orow < n) {
            #pragma unroll
            for (int ct = 0; ct < 6; ct++) {
                int col = ct * 16 + lid;
                float v = o[ct][rg];
                h[(size_t)orow * HID + col] = v;
                float y = fmaxf((v - mu) * rs * lng[col] + lnb[col], 0.f);
                unsigned short hi = f32_to_bf16_rne(y);
                hn_hi[(size_t)orow * HID + col] = hi;
                hn_lo[(size_t)orow * HID + col] = f32_to_bf16_rne(y - bf16_to_f32(hi));
            }
        }
    }
}

// ---------------- layer GEMMs via split-bf16 MFMA (LDS-staged B, 16 rows/wave) ----------------
__global__ __launch_bounds__(256) void k_gemm2_mfma(
        const unsigned short* __restrict__ hn_hi, const unsigned short* __restrict__ hn_lo,
        const unsigned short* __restrict__ wf_hi, const unsigned short* __restrict__ wf_lo,
        const float* __restrict__ bl, const float* __restrict__ br,
        unsigned short* __restrict__ xl_h, unsigned short* __restrict__ xr_h, int n) {
    __shared__ unsigned short lh[9216];
    __shared__ unsigned short ll[9216];
    int t = threadIdx.x;
    int wave = t >> 6, lane = t & 63;
    int quad = lane >> 4, lid = lane & 15;
    int r0 = blockIdx.x * 64 + wave * 16;
    int arow = r0 + lid; if (arow >= n) arow = n - 1;
    short8 aH[3], aL[3];
    #pragma unroll
    for (int s = 0; s < 3; s++) {
        aH[s] = *(const short8*)(hn_hi + (size_t)arow * HID + s * 32 + quad * 8);
        aL[s] = *(const short8*)(hn_lo + (size_t)arow * HID + s * 32 + quad * 8);
    }
    for (int lr = 0; lr < 2; lr++) {
        const unsigned short* sh = wf_hi + lr * 9216;
        const unsigned short* sl = wf_lo + lr * 9216;
        __syncthreads();
        for (int u = t; u < 1152; u += 256) {
            *(short8*)(lh + u * 8) = *(const short8*)(sh + u * 8);
            *(short8*)(ll + u * 8) = *(const short8*)(sl + u * 8);
        }
        __syncthreads();
        const float* bias = lr ? br : bl;
        unsigned short* out = lr ? xr_h : xl_h;
        #pragma unroll
        for (int ct = 0; ct < 6; ct++) {
            floatx4 acc = {0.f, 0.f, 0.f, 0.f};
            #pragma unroll
            for (int s = 0; s < 3; s++) {
                short8 bH = *(const short8*)(lh + ((ct * 3 + s) * 64 + lane) * 8);
                short8 bL = *(const short8*)(ll + ((ct * 3 + s) * 64 + lane) * 8);
                acc = __builtin_amdgcn_mfma_f32_16x16x32_bf16(aH[s], bH, acc, 0, 0, 0);
                acc = __builtin_amdgcn_mfma_f32_16x16x32_bf16(aH[s], bL, acc, 0, 0, 0);
                acc = __builtin_amdgcn_mfma_f32_16x16x32_bf16(aL[s], bH, acc, 0, 0, 0);
            }
            int col = ct * 16 + lid;
            float bv = bias[col];
            #pragma unroll
            for (int rg = 0; rg < 4; rg++) {
                int orow = r0 + quad * 4 + rg;
                if (orow < n) {
                    _Float16 hv = (_Float16)(acc[rg] + bv);
                    out[(size_t)orow * HID + col] = *(unsigned short*)&hv;
                }
            }
        }
    }
}

// ---------------- fused GATv2 + residual + next-layer LN (or final LN+fc) ----------------
__global__ __launch_bounds__(256) void k_gat_fused(
        const unsigned short* __restrict__ xl_h, const unsigned short* __restrict__ xr_h,
        const unsigned* __restrict__ ep, const int* __restrict__ rowptr,
        const float* __restrict__ We, const float* __restrict__ att, const float* __restrict__ bias,
        float* __restrict__ h,
        unsigned short* __restrict__ hn_hi, unsigned short* __restrict__ hn_lo,
        float* __restrict__ out_final,
        const float* __restrict__ g, const float* __restrict__ bt,
        const float* __restrict__ fcW, const float* __restrict__ fcb,
        int mode, int n) {
    int lane = threadIdx.x & 63;
    int node = blockIdx.x * 4 + (threadIdx.x >> 6);
    if (node >= n) return;
    int grp = lane >> 4, sub = lane & 15;
    int d0 = sub * 6;
    unsigned gOffB = (unsigned)(sub * 12);

    const float LOG2E = 1.4426950408889634f;
    union U6 { u96 u; half2v h2[3]; _Float16 hf[6]; };
    half2v we_h[3], at_h[3], xr_hv[3];
    {
        U6 xrw;
        xrw.u = *(const u96*)((const char*)xr_h + ((unsigned)node * 192u + gOffB));
        float2 a0 = *(const float2*)(We + d0);
        float2 a1 = *(const float2*)(We + d0 + 2);
        float2 a2 = *(const float2*)(We + d0 + 4);
        float2 c0 = *(const float2*)(att + d0);
        float2 c1 = *(const float2*)(att + d0 + 2);
        float2 c2 = *(const float2*)(att + d0 + 4);
        we_h[0] = half2v{(_Float16)a0.x, (_Float16)a0.y};
        we_h[1] = half2v{(_Float16)a1.x, (_Float16)a1.y};
        we_h[2] = half2v{(_Float16)a2.x, (_Float16)a2.y};
        at_h[0] = half2v{(_Float16)(c0.x*LOG2E), (_Float16)(c0.y*LOG2E)};
        at_h[1] = half2v{(_Float16)(c1.x*LOG2E), (_Float16)(c1.y*LOG2E)};
        at_h[2] = half2v{(_Float16)(c2.x*LOG2E), (_Float16)(c2.y*LOG2E)};
        #pragma unroll
        for (int j = 0; j < 3; j++) xr_hv[j] = xrw.h2[j];
    }
    const half2v c02 = half2v{(_Float16)0.2f, (_Float16)0.2f};

    int beg = rowptr[node], end = rowptr[node + 1];
    float ssum = 0.f;
    float acc[6];
    #pragma unroll
    for (int j = 0; j < 6; j++) acc[j] = 0.f;

    auto lq = [&](int p, u96& vraw, _Float16& wh, bool& val) {
        int pe = p + grp;
        val = pe < end;
        int pc = val ? pe : end - 1;
        unsigned e = ep[pc];
        unsigned short wb = (unsigned short)(e >> 16);
        wh = *(_Float16*)&wb;
        vraw = *(const u96*)((const char*)xl_h + ((e & 0xFFFFu) * 192u + gOffB));
    };
    auto proc = [&](const u96& vraw, _Float16 wh, bool val) {
        U6 cv; cv.u = vraw;
        half2v w2 = half2v{wh, wh};
        float q = 0.f;
        #pragma unroll
        for (int j = 0; j < 3; j++) {
            half2v t = cv.h2[j] + xr_hv[j];
            t = w2 * we_h[j] + t;
            half2v t2 = t * c02;
            t = __builtin_elementwise_max(t, t2);
#if __has_builtin(__builtin_amdgcn_fdot2)
            q = __builtin_amdgcn_fdot2(t, at_h[j], q, false);
#else
            q = fmaf((float)t[0], (float)at_h[j][0], q);
            q = fmaf((float)t[1], (float)at_h[j][1], q);
#endif
        }
        q += __shfl_xor(q, 1); q += __shfl_xor(q, 2);
        q += __shfl_xor(q, 4); q += __shfl_xor(q, 8);
        float e = val ? exp2f(q) : 0.f;
        ssum += e;
        #pragma unroll
        for (int j = 0; j < 6; j++) acc[j] = fmaf((float)cv.hf[j], e, acc[j]);
    };

    if (beg < end) {
        u96 vA, vB; _Float16 wA, wB; bool okA, okB;
        lq(beg,     vA, wA, okA);
        lq(beg + 4, vB, wB, okB);
        for (int p = beg; p < end; p += 8) {
            proc(vA, wA, okA);
            lq(p + 8, vA, wA, okA);
            proc(vB, wB, okB);
            lq(p + 12, vB, wB, okB);
        }
    }

    ssum += __shfl_xor(ssum, 16); ssum += __shfl_xor(ssum, 32);
    #pragma unroll
    for (int j = 0; j < 6; j++) {
        acc[j] += __shfl_xor(acc[j], 16);
        acc[j] += __shfl_xor(acc[j], 32);
    }
    float inv = 1.f / (ssum + 1e-16f);

    float nh[6];
    float s1 = 0.f, s2 = 0.f;
    {
        float2 h0 = *(const float2*)(h + (size_t)node * HID + d0);
        float2 h1 = *(const float2*)(h + (size_t)node * HID + d0 + 2);
        float2 h2 = *(const float2*)(h + (size_t)node * HID + d0 + 4);
        float2 b0 = *(const float2*)(bias + d0);
        float2 b1 = *(const float2*)(bias + d0 + 2);
        float2 b2 = *(const float2*)(bias + d0 + 4);
        float hv[6] = {h0.x, h0.y, h1.x, h1.y, h2.x, h2.y};
        float bv[6] = {b0.x, b0.y, b1.x, b1.y, b2.x, b2.y};
        #pragma unroll
        for (int j = 0; j < 6; j++) {
            nh[j] = hv[j] + acc[j] * inv + bv[j];
            s1 += nh[j];
            s2 += nh[j] * nh[j];
        }
    }
    #pragma unroll
    for (int off = 1; off < 16; off <<= 1) {
        s1 += __shfl_xor(s1, off);
        s2 += __shfl_xor(s2, off);
    }
    float mu = s1 * (1.f / 96.f);
    float var = s2 * (1.f / 96.f) - mu * mu;
    float rs = rsqrtf(var + 1e-5f);

    if (mode == 0) {
        if (grp == 0) {
            float2 g0 = *(const float2*)(g + d0);
            float2 g1 = *(const float2*)(g + d0 + 2);
            float2 g2 = *(const float2*)(g + d0 + 4);
            float2 t0 = *(const float2*)(bt + d0);
            float2 t1 = *(const float2*)(bt + d0 + 2);
            float2 t2 = *(const float2*)(bt + d0 + 4);
            float gv[6] = {g0.x, g0.y, g1.x, g1.y, g2.x, g2.y};
            float tv[6] = {t0.x, t0.y, t1.x, t1.y, t2.x, t2.y};
            *(float2*)(h + (size_t)node * HID + d0)     = make_float2(nh[0], nh[1]);
            *(float2*)(h + (size_t)node * HID + d0 + 2) = make_float2(nh[2], nh[3]);
            *(float2*)(h + (size_t)node * HID + d0 + 4) = make_float2(nh[4], nh[5]);
            unsigned hi[3], lo[3];
            #pragma unroll
            for (int j = 0; j < 3; j++) {
                float ox = fmaxf((nh[2*j]   - mu) * rs * gv[2*j]   + tv[2*j],   0.f);
                float oy = fmaxf((nh[2*j+1] - mu) * rs * gv[2*j+1] + tv[2*j+1], 0.f);
                unsigned short hx = f32_to_bf16_rne(ox), hy = f32_to_bf16_rne(oy);
                unsigned short lx = f32_to_bf16_rne(ox - bf16_to_f32(hx));
                unsigned short ly = f32_to_bf16_rne(oy - bf16_to_f32(hy));
                hi[j] = (unsigned)hx | ((unsigned)hy << 16);
                lo[j] = (unsigned)lx | ((unsigned)ly << 16);
            }
            u96 wh = {hi[0], hi[1], hi[2]};
            u96 wl = {lo[0], lo[1], lo[2]};
            *(u96*)((char*)hn_hi + 2 * ((size_t)node * HID + d0)) = wh;
            *(u96*)((char*)hn_lo + 2 * ((size_t)node * HID + d0)) = wl;
        }
    } else {
        float pacc = 0.f;
        {
            float2 g0 = *(const float2*)(g + d0);
            float2 g1 = *(const float2*)(g + d0 + 2);
            float2 g2 = *(const float2*)(g + d0 + 4);
            float2 t0 = *(const float2*)(bt + d0);
            float2 t1 = *(const float2*)(bt + d0 + 2);
            float2 t2 = *(const float2*)(bt + d0 + 4);
            float2 w0 = *(const float2*)(fcW + d0);
            float2 w1 = *(const float2*)(fcW + d0 + 2);
            float2 w2 = *(const float2*)(fcW + d0 + 4);
            float gv[6] = {g0.x, g0.y, g1.x, g1.y, g2.x, g2.y};
            float tv[6] = {t0.x, t0.y, t1.x, t1.y, t2.x, t2.y};
            float wv[6] = {w0.x, w0.y, w1.x, w1.y, w2.x, w2.y};
            #pragma unroll
            for (int j = 0; j < 6; j++) {
                float y = fmaxf((nh[j] - mu) * rs * gv[j] + tv[j], 0.f);
                pacc = fmaf(y, wv[j], pacc);
            }
        }
        #pragma unroll
        for (int off = 1; off < 16; off <<= 1) pacc += __shfl_xor(pacc, off);
        if (lane == 0) out_final[node] = pacc + fcb[0];
    }
}

extern "C" void kernel_launch(void* const* d_in, const int* in_sizes, int n_in,
                              void* d_out, int out_size, void* d_ws, size_t ws_size,
                              hipStream_t stream) {
    const float* x    = (const float*)d_in[0];
    const int*   ei   = (const int*)  d_in[1];
    const float* ew   = (const float*)d_in[2];
    const float* encW = (const float*)d_in[3];
    const float* encB = (const float*)d_in[4];
    const float* Wl   = (const float*)d_in[5];
    const float* bl   = (const float*)d_in[6];
    const float* Wr   = (const float*)d_in[7];
    const float* br   = (const float*)d_in[8];
    const float* We   = (const float*)d_in[9];
    const float* att  = (const float*)d_in[10];
    const float* bias = (const float*)d_in[11];
    const float* lng  = (const float*)d_in[12];
    const float* lnb  = (const float*)d_in[13];
    const float* lnfg = (const float*)d_in[14];
    const float* lnfb = (const float*)d_in[15];
    const float* fcW  = (const float*)d_in[16];
    const float* fcb  = (const float*)d_in[17];
    float* out = (float*)d_out;

    const int* src = ei;
    const int* dst = ei + EE;

    char* ws = (char*)d_ws;
    size_t off = 0;
    auto alloc = [&](size_t bytes) -> void* {
        void* p = ws + off;
        off += (bytes + 255) & ~(size_t)255;
        return p;
    };
    float* h      = (float*)alloc((size_t)NN * HID * 4);
    unsigned short* xl_h  = (unsigned short*)alloc((size_t)NN * HID * 2 + 256);
    unsigned short* xr_h  = (unsigned short*)alloc((size_t)NN * HID * 2 + 256);
    unsigned short* hn_hi = (unsigned short*)alloc((size_t)NN * HID * 2);
    unsigned short* hn_lo = (unsigned short*)alloc((size_t)NN * HID * 2);
    unsigned short* wf_hi = (unsigned short*)alloc((size_t)WPREP_L * 2);
    unsigned short* wf_lo = (unsigned short*)alloc((size_t)WPREP_L * 2);
    unsigned short* we_hi = (unsigned short*)alloc(12288 * 2);
    unsigned short* we_lo = (unsigned short*)alloc(12288 * 2);
    int*   deg    = (int*)  alloc((size_t)NN * 4);
    int*   rowptr = (int*)  alloc((size_t)(NN + 1) * 4);
    int*   cursor = (int*)  alloc((size_t)NN * 4);
    unsigned* epack = (unsigned*)alloc((size_t)EE * 4);
    uint2* ibuf   = (uint2*)alloc((size_t)NBUCK * BCAP * 8);
    int*   gcur   = (int*)  alloc(NBUCK * 4);
    int*   parts  = (int*)  alloc(256 * 4);

    const int NB = (NN + CHUNK - 1) / CHUNK;       // 49
    const int EB = (EE + 255) / 256;               // 3125
    const int PB = (EE + PH1E - 1) / PH1E;         // 196
    const int MB = (NN + 63) / 64;                 // 782
    const int WB = (NN + 3) / 4;                   // 12500

    // CSR build
    hipMemsetAsync(deg, 0, (size_t)NN * 4, stream);
    hipMemsetAsync(gcur, 0, NBUCK * 4, stream);
    k_hist<<<EB, 256, 0, stream>>>(dst, deg, EE);
    k_binscatter<<<PB, 256, 0, stream>>>(src, dst, ew, gcur, ibuf, EE);
    k_scan1<<<NB, 256, 0, stream>>>(deg, parts, NN);
    k_scan_mid<<<1, 64, 0, stream>>>(parts, NB, rowptr, NN);
    k_scan3<<<NB, 256, 0, stream>>>(deg, parts, rowptr, cursor, NN);
    k_binplace<<<NBUCK, 256, 0, stream>>>(ibuf, gcur, rowptr, epack, NN);

    // weight prep
    k_wprep_all<<<(WPREP_TOT + 255) / 256, 256, 0, stream>>>(Wl, Wr, encW, wf_hi, wf_lo, we_hi, we_lo);

    // encoder (+fused first LN)
    k_enc_mfma<<<MB, 256, 0, stream>>>(x, we_hi, we_lo, encB, lng, lnb, h, hn_hi, hn_lo, NN);

    for (int l = 0; l < NL; l++) {
        k_gemm2_mfma<<<MB, 256, 0, stream>>>(hn_hi, hn_lo,
            wf_hi + (size_t)l * 2 * 9216, wf_lo + (size_t)l * 2 * 9216,
            bl + l * HID, br + l * HID, xl_h, xr_h, NN);
        if (l < NL - 1) {
            k_gat_fused<<<WB, 256, 0, stream>>>(xl_h, xr_h, epack, rowptr,
                We + l * HID, att + l * HID, bias + l * HID,
                h, hn_hi, hn_lo, (float*)nullptr,
                lng + (l + 1) * HID, lnb + (l + 1) * HID,
                (const float*)nullptr, (const float*)nullptr, 0, NN);
        } else {
            k_gat_fused<<<WB, 256, 0, stream>>>(xl_h, xr_h, epack, rowptr,
                We + l * HID, att + l * HID, bias + l * HID,
                h, (unsigned short*)nullptr, (unsigned short*)nullptr, out,
                lnfg, lnfb, fcW, fcb, 1, NN);
        }
    }
}

// Round 16
// 435.390 us; speedup vs baseline: 1.1418x; 1.0365x over previous
//
#include <hip/hip_runtime.h>
#include <math.h>

#define NN 50000
#define EE 800000
#define FIN 128
#define HID 96
#define NL 4
#define CHUNK 1024

typedef __attribute__((ext_vector_type(8))) short short8;
typedef __attribute__((ext_vector_type(4))) float floatx4;
typedef __attribute__((ext_vector_type(2))) _Float16 half2v;

#define WPREP_L (NL * 2 * 9216)       // 73728
#define WPREP_TOT (WPREP_L + 12288)   // 86016

#define PH1E 4096
#define NBUCK 98
#define BCAP 9216

struct u96 { unsigned x, y, z; };

__device__ __forceinline__ unsigned short f16bits(float x) {
    _Float16 h = (_Float16)x;
    return *(unsigned short*)&h;
}

// ---------------- CSR build ----------------
__global__ void k_scan1(const int* __restrict__ deg, int* __restrict__ partials, int n) {
    __shared__ int lds[256];
    int t = threadIdx.x;
    int base = blockIdx.x * CHUNK + t * 4;
    int s = 0;
    #pragma unroll
    for (int q = 0; q < 4; q++) { int idx = base + q; if (idx < n) s += deg[idx]; }
    lds[t] = s; __syncthreads();
    for (int o = 128; o > 0; o >>= 1) { if (t < o) lds[t] += lds[t + o]; __syncthreads(); }
    if (t == 0) partials[blockIdx.x] = lds[0];
}

__global__ void k_scan_mid(int* partials, int nb, int* rowptr, int n) {
    int lane = threadIdx.x;
    int orig = (lane < nb) ? partials[lane] : 0;
    int v = orig;
    #pragma unroll
    for (int off = 1; off < 64; off <<= 1) {
        int u = __shfl_up(v, off);
        if (lane >= off) v += u;
    }
    if (lane < nb) partials[lane] = v - orig;
    if (lane == 63) rowptr[n] = v;
}

__global__ void k_scan3(const int* __restrict__ deg, const int* __restrict__ partials,
                        int* __restrict__ rowptr, int* __restrict__ cursor, int n) {
    __shared__ int lds[256];
    int t = threadIdx.x;
    int base = blockIdx.x * CHUNK + t * 4;
    int v[4];
    #pragma unroll
    for (int q = 0; q < 4; q++) { int idx = base + q; v[q] = (idx < n) ? deg[idx] : 0; }
    int tsum = v[0] + v[1] + v[2] + v[3];
    lds[t] = tsum; __syncthreads();
    for (int o = 1; o < 256; o <<= 1) {
        int add = (t >= o) ? lds[t - o] : 0;
        __syncthreads();
        lds[t] += add;
        __syncthreads();
    }
    int excl = lds[t] - tsum;
    int run = partials[blockIdx.x] + excl;
    #pragma unroll
    for (int q = 0; q < 4; q++) {
        int idx = base + q;
        if (idx < n) { rowptr[idx] = run; cursor[idx] = run; run += v[q]; }
    }
}

// ---------------- two-phase binned scatter (hist fused into phase 1) ----------------
__global__ __launch_bounds__(256) void k_binscatter(const int* __restrict__ src,
        const int* __restrict__ dst, const float* __restrict__ ew,
        int* __restrict__ deg, int* __restrict__ gcur, uint2* __restrict__ ibuf, int E) {
    __shared__ uint2 st[PH1E];
    __shared__ int cnt[NBUCK], off[NBUCK], cur[NBUCK], gbase[NBUCK];
    int t = threadIdx.x;
    int e0 = blockIdx.x * PH1E;
    for (int i = t; i < NBUCK; i += 256) { cnt[i] = 0; cur[i] = 0; }
    __syncthreads();
    #pragma unroll
    for (int k = 0; k < PH1E / 256; k++) {
        int e = e0 + k * 256 + t;
        if (e < E) {
            int d = dst[e];
            atomicAdd(&cnt[d >> 9], 1);
            atomicAdd(&deg[d], 1);          // fused global histogram
        }
    }
    __syncthreads();
    if (t == 0) {
        int run = 0;
        for (int b = 0; b < NBUCK; b++) { off[b] = run; run += cnt[b]; }
    }
    __syncthreads();
    #pragma unroll
    for (int k = 0; k < PH1E / 256; k++) {
        int e = e0 + k * 256 + t;
        if (e < E) {
            int d = dst[e];
            int b = d >> 9;
            int p = off[b] + atomicAdd(&cur[b], 1);
            unsigned short wb = f16bits(ew[e]);
            st[p] = make_uint2((unsigned)d, (unsigned)src[e] | ((unsigned)wb << 16));
        }
    }
    __syncthreads();
    if (t < NBUCK) gbase[t] = atomicAdd(&gcur[t], cur[t]);
    __syncthreads();
    int total = min(PH1E, E - e0);
    for (int i = t; i < total; i += 256) {
        uint2 v = st[i];
        int b = v.x >> 9;
        ibuf[(size_t)b * BCAP + gbase[b] + (i - off[b])] = v;
    }
}

__global__ __launch_bounds__(256) void k_binplace(const uint2* __restrict__ ibuf,
        const int* __restrict__ gcur, const int* __restrict__ rowptr,
        unsigned* __restrict__ epack, int n) {
    __shared__ int cur[512];
    int t = threadIdx.x;
    int b = blockIdx.x;
    int n0 = b << 9;
    for (int i = t; i < 512; i += 256) {
        int node = n0 + i;
        cur[i] = (node < n) ? rowptr[node] : 0;
    }
    __syncthreads();
    int nb = gcur[b];
    for (int i = t; i < nb; i += 256) {
        uint2 v = ibuf[(size_t)b * BCAP + i];
        int p = atomicAdd(&cur[(int)v.x - n0], 1);
        epack[p] = v.y;
    }
}

// ---------------- merged weight prep: fp16 B-fragment layouts ----------------
__global__ void k_wprep_all(const float* __restrict__ Wl, const float* __restrict__ Wr,
                            const float* __restrict__ encW,
                            unsigned short* __restrict__ wf, unsigned short* __restrict__ we) {
    int t = blockIdx.x * blockDim.x + threadIdx.x;
    if (t < WPREP_L) {
        int within = t % 9216, pair = t / 9216;
        int lr = pair & 1, layer = pair >> 1;
        int j = within & 7;
        int lane = (within >> 3) & 63;
        int cs = within >> 9;
        int s = cs % 3, ct = cs / 3;
        int col = ct * 16 + (lane & 15);
        int k = s * 32 + (lane >> 4) * 8 + j;
        const float* W = (lr ? Wr : Wl) + (size_t)layer * HID * HID;
        wf[t] = f16bits(W[k * HID + col]);
    } else if (t < WPREP_TOT) {
        int u = t - WPREP_L;
        int j = u & 7;
        int lane = (u >> 3) & 63;
        int cs = u >> 9;
        int s = cs & 3, ct = cs >> 2;
        int col = ct * 16 + (lane & 15);
        int k = s * 32 + (lane >> 4) * 8 + j;
        we[u] = f16bits(encW[k * HID + col]);
    }
}

// ---------------- encoder via fp16 MFMA + fused LN/relu epilogue ----------------
__global__ __launch_bounds__(256) void k_enc_mfma(const float* __restrict__ x,
        const unsigned short* __restrict__ we,
        const float* __restrict__ b,
        const float* __restrict__ lng, const float* __restrict__ lnb,
        float* __restrict__ h,
        unsigned short* __restrict__ hn, int n) {
    int t = threadIdx.x;
    int wave = t >> 6, lane = t & 63;
    int quad = lane >> 4, lid = lane & 15;
    int r0 = blockIdx.x * 64 + wave * 16;
    int arow = r0 + lid; if (arow >= n) arow = n - 1;
    short8 aF[4];
    #pragma unroll
    for (int s = 0; s < 4; s++) {
        float4 p0 = *(const float4*)(x + (size_t)arow * FIN + s * 32 + quad * 8);
        float4 p1 = *(const float4*)(x + (size_t)arow * FIN + s * 32 + quad * 8 + 4);
        float f[8] = {p0.x, p0.y, p0.z, p0.w, p1.x, p1.y, p1.z, p1.w};
        #pragma unroll
        for (int j = 0; j < 8; j++) aF[s][j] = (short)f16bits(f[j]);
    }
    floatx4 o[6];
    #pragma unroll
    for (int ct = 0; ct < 6; ct++) {
        floatx4 acc = {0.f, 0.f, 0.f, 0.f};
        #pragma unroll
        for (int s = 0; s < 4; s++) {
            short8 bF = *(const short8*)(we + ((ct * 4 + s) * 64 + lane) * 8);
            acc = __builtin_amdgcn_mfma_f32_16x16x32_f16(aF[s], bF, acc, 0, 0, 0);
        }
        float bv = b[ct * 16 + lid];
        #pragma unroll
        for (int rg = 0; rg < 4; rg++) o[ct][rg] = acc[rg] + bv;
    }
    #pragma unroll
    for (int rg = 0; rg < 4; rg++) {
        float s1 = 0.f, s2 = 0.f;
        #pragma unroll
        for (int ct = 0; ct < 6; ct++) { s1 += o[ct][rg]; s2 += o[ct][rg] * o[ct][rg]; }
        #pragma unroll
        for (int off = 1; off < 16; off <<= 1) {
            s1 += __shfl_xor(s1, off);
            s2 += __shfl_xor(s2, off);
        }
        float mu = s1 * (1.f / 96.f);
        float var = s2 * (1.f / 96.f) - mu * mu;
        float rs = rsqrtf(var + 1e-5f);
        int orow = r0 + quad * 4 + rg;
        if (orow < n) {
            #pragma unroll
            for (int ct = 0; ct < 6; ct++) {
                int col = ct * 16 + lid;
                float v = o[ct][rg];
                h[(size_t)orow * HID + col] = v;
                float y = fmaxf((v - mu) * rs * lng[col] + lnb[col], 0.f);
                hn[(size_t)orow * HID + col] = f16bits(y);
            }
        }
    }
}

// ---------------- layer GEMMs via fp16 MFMA (LDS-staged B) ----------------
__global__ __launch_bounds__(256) void k_gemm2_mfma(
        const unsigned short* __restrict__ hn,
        const unsigned short* __restrict__ wf,
        const float* __restrict__ bl, const float* __restrict__ br,
        unsigned short* __restrict__ xl_h, unsigned short* __restrict__ xr_h, int n) {
    __shared__ unsigned short lw[9216];
    int t = threadIdx.x;
    int wave = t >> 6, lane = t & 63;
    int quad = lane >> 4, lid = lane & 15;
    int r0 = blockIdx.x * 64 + wave * 16;
    int arow = r0 + lid; if (arow >= n) arow = n - 1;
    short8 aF[3];
    #pragma unroll
    for (int s = 0; s < 3; s++)
        aF[s] = *(const short8*)(hn + (size_t)arow * HID + s * 32 + quad * 8);
    for (int lr = 0; lr < 2; lr++) {
        const unsigned short* sw = wf + lr * 9216;
        __syncthreads();
        for (int u = t; u < 1152; u += 256)
            *(short8*)(lw + u * 8) = *(const short8*)(sw + u * 8);
        __syncthreads();
        const float* bias = lr ? br : bl;
        unsigned short* out = lr ? xr_h : xl_h;
        #pragma unroll
        for (int ct = 0; ct < 6; ct++) {
            floatx4 acc = {0.f, 0.f, 0.f, 0.f};
            #pragma unroll
            for (int s = 0; s < 3; s++) {
                short8 bF = *(const short8*)(lw + ((ct * 3 + s) * 64 + lane) * 8);
                acc = __builtin_amdgcn_mfma_f32_16x16x32_f16(aF[s], bF, acc, 0, 0, 0);
            }
            int col = ct * 16 + lid;
            float bv = bias[col];
            #pragma unroll
            for (int rg = 0; rg < 4; rg++) {
                int orow = r0 + quad * 4 + rg;
                if (orow < n) out[(size_t)orow * HID + col] = f16bits(acc[rg] + bv);
            }
        }
    }
}

// ---------------- fused GATv2 + residual + next-layer LN (or final LN+fc) ----------------
__global__ __launch_bounds__(256) void k_gat_fused(
        const unsigned short* __restrict__ xl_h, const unsigned short* __restrict__ xr_h,
        const unsigned* __restrict__ ep, const int* __restrict__ rowptr,
        const float* __restrict__ We, const float* __restrict__ att, const float* __restrict__ bias,
        float* __restrict__ h,
        unsigned short* __restrict__ hn,
        float* __restrict__ out_final,
        const float* __restrict__ g, const float* __restrict__ bt,
        const float* __restrict__ fcW, const float* __restrict__ fcb,
        int mode, int n) {
    int lane = threadIdx.x & 63;
    int node = blockIdx.x * 4 + (threadIdx.x >> 6);
    if (node >= n) return;
    int grp = lane >> 4, sub = lane & 15;
    int d0 = sub * 6;
    unsigned gOffB = (unsigned)(sub * 12);

    const float LOG2E = 1.4426950408889634f;
    union U6 { u96 u; half2v h2[3]; _Float16 hf[6]; };
    half2v we_h[3], at_h[3], xr_hv[3];
    {
        U6 xrw;
        xrw.u = *(const u96*)((const char*)xr_h + ((unsigned)node * 192u + gOffB));
        float2 a0 = *(const float2*)(We + d0);
        float2 a1 = *(const float2*)(We + d0 + 2);
        float2 a2 = *(const float2*)(We + d0 + 4);
        float2 c0 = *(const float2*)(att + d0);
        float2 c1 = *(const float2*)(att + d0 + 2);
        float2 c2 = *(const float2*)(att + d0 + 4);
        we_h[0] = half2v{(_Float16)a0.x, (_Float16)a0.y};
        we_h[1] = half2v{(_Float16)a1.x, (_Float16)a1.y};
        we_h[2] = half2v{(_Float16)a2.x, (_Float16)a2.y};
        at_h[0] = half2v{(_Float16)(c0.x*LOG2E), (_Float16)(c0.y*LOG2E)};
        at_h[1] = half2v{(_Float16)(c1.x*LOG2E), (_Float16)(c1.y*LOG2E)};
        at_h[2] = half2v{(_Float16)(c2.x*LOG2E), (_Float16)(c2.y*LOG2E)};
        #pragma unroll
        for (int j = 0; j < 3; j++) xr_hv[j] = xrw.h2[j];
    }
    const half2v c02 = half2v{(_Float16)0.2f, (_Float16)0.2f};

    int beg = rowptr[node], end = rowptr[node + 1];
    float ssum = 0.f;
    float acc[6];
    #pragma unroll
    for (int j = 0; j < 6; j++) acc[j] = 0.f;

    auto lq = [&](int p, u96& vraw, _Float16& wh, bool& val) {
        int pe = p + grp;
        val = pe < end;
        int pc = val ? pe : end - 1;
        unsigned e = ep[pc];
        unsigned short wb = (unsigned short)(e >> 16);
        wh = *(_Float16*)&wb;
        vraw = *(const u96*)((const char*)xl_h + ((e & 0xFFFFu) * 192u + gOffB));
    };
    auto proc = [&](const u96& vraw, _Float16 wh, bool val) {
        U6 cv; cv.u = vraw;
        half2v w2 = half2v{wh, wh};
        float q = 0.f;
        #pragma unroll
        for (int j = 0; j < 3; j++) {
            half2v t = cv.h2[j] + xr_hv[j];
            t = w2 * we_h[j] + t;
            half2v t2 = t * c02;
            t = __builtin_elementwise_max(t, t2);
#if __has_builtin(__builtin_amdgcn_fdot2)
            q = __builtin_amdgcn_fdot2(t, at_h[j], q, false);
#else
            q = fmaf((float)t[0], (float)at_h[j][0], q);
            q = fmaf((float)t[1], (float)at_h[j][1], q);
#endif
        }
        q += __shfl_xor(q, 1); q += __shfl_xor(q, 2);
        q += __shfl_xor(q, 4); q += __shfl_xor(q, 8);
        float e = val ? exp2f(q) : 0.f;
        ssum += e;
        #pragma unroll
        for (int j = 0; j < 6; j++) acc[j] = fmaf((float)cv.hf[j], e, acc[j]);
    };

    if (beg < end) {
        u96 vA, vB; _Float16 wA, wB; bool okA, okB;
        lq(beg,     vA, wA, okA);
        lq(beg + 4, vB, wB, okB);
        for (int p = beg; p < end; p += 8) {
            proc(vA, wA, okA);
            lq(p + 8, vA, wA, okA);
            proc(vB, wB, okB);
            lq(p + 12, vB, wB, okB);
        }
    }

    ssum += __shfl_xor(ssum, 16); ssum += __shfl_xor(ssum, 32);
    #pragma unroll
    for (int j = 0; j < 6; j++) {
        acc[j] += __shfl_xor(acc[j], 16);
        acc[j] += __shfl_xor(acc[j], 32);
    }
    float inv = 1.f / (ssum + 1e-16f);

    float nh[6];
    float s1 = 0.f, s2 = 0.f;
    {
        float2 h0 = *(const float2*)(h + (size_t)node * HID + d0);
        float2 h1 = *(const float2*)(h + (size_t)node * HID + d0 + 2);
        float2 h2 = *(const float2*)(h + (size_t)node * HID + d0 + 4);
        float2 b0 = *(const float2*)(bias + d0);
        float2 b1 = *(const float2*)(bias + d0 + 2);
        float2 b2 = *(const float2*)(bias + d0 + 4);
        float hv[6] = {h0.x, h0.y, h1.x, h1.y, h2.x, h2.y};
        float bv[6] = {b0.x, b0.y, b1.x, b1.y, b2.x, b2.y};
        #pragma unroll
        for (int j = 0; j < 6; j++) {
            nh[j] = hv[j] + acc[j] * inv + bv[j];
            s1 += nh[j];
            s2 += nh[j] * nh[j];
        }
    }
    #pragma unroll
    for (int off = 1; off < 16; off <<= 1) {
        s1 += __shfl_xor(s1, off);
        s2 += __shfl_xor(s2, off);
    }
    float mu = s1 * (1.f / 96.f);
    float var = s2 * (1.f / 96.f) - mu * mu;
    float rs = rsqrtf(var + 1e-5f);

    if (mode == 0) {
        if (grp == 0) {
            float2 g0 = *(const float2*)(g + d0);
            float2 g1 = *(const float2*)(g + d0 + 2);
            float2 g2 = *(const float2*)(g + d0 + 4);
            float2 t0 = *(const float2*)(bt + d0);
            float2 t1 = *(const float2*)(bt + d0 + 2);
            float2 t2 = *(const float2*)(bt + d0 + 4);
            float gv[6] = {g0.x, g0.y, g1.x, g1.y, g2.x, g2.y};
            float tv[6] = {t0.x, t0.y, t1.x, t1.y, t2.x, t2.y};
            *(float2*)(h + (size_t)node * HID + d0)     = make_float2(nh[0], nh[1]);
            *(float2*)(h + (size_t)node * HID + d0 + 2) = make_float2(nh[2], nh[3]);
            *(float2*)(h + (size_t)node * HID + d0 + 4) = make_float2(nh[4], nh[5]);
            unsigned w[3];
            #pragma unroll
            for (int j = 0; j < 3; j++) {
                float ox = fmaxf((nh[2*j]   - mu) * rs * gv[2*j]   + tv[2*j],   0.f);
                float oy = fmaxf((nh[2*j+1] - mu) * rs * gv[2*j+1] + tv[2*j+1], 0.f);
                w[j] = (unsigned)f16bits(ox) | ((unsigned)f16bits(oy) << 16);
            }
            u96 wv6 = {w[0], w[1], w[2]};
            *(u96*)((char*)hn + 2 * ((size_t)node * HID + d0)) = wv6;
        }
    } else {
        float pacc = 0.f;
        {
            float2 g0 = *(const float2*)(g + d0);
            float2 g1 = *(const float2*)(g + d0 + 2);
            float2 g2 = *(const float2*)(g + d0 + 4);
            float2 t0 = *(const float2*)(bt + d0);
            float2 t1 = *(const float2*)(bt + d0 + 2);
            float2 t2 = *(const float2*)(bt + d0 + 4);
            float2 w0 = *(const float2*)(fcW + d0);
            float2 w1 = *(const float2*)(fcW + d0 + 2);
            float2 w2 = *(const float2*)(fcW + d0 + 4);
            float gv[6] = {g0.x, g0.y, g1.x, g1.y, g2.x, g2.y};
            float tv[6] = {t0.x, t0.y, t1.x, t1.y, t2.x, t2.y};
            float wv[6] = {w0.x, w0.y, w1.x, w1.y, w2.x, w2.y};
            #pragma unroll
            for (int j = 0; j < 6; j++) {
                float y = fmaxf((nh[j] - mu) * rs * gv[j] + tv[j], 0.f);
                pacc = fmaf(y, wv[j], pacc);
            }
        }
        #pragma unroll
        for (int off = 1; off < 16; off <<= 1) pacc += __shfl_xor(pacc, off);
        if (lane == 0) out_final[node] = pacc + fcb[0];
    }
}

extern "C" void kernel_launch(void* const* d_in, const int* in_sizes, int n_in,
                              void* d_out, int out_size, void* d_ws, size_t ws_size,
                              hipStream_t stream) {
    const float* x    = (const float*)d_in[0];
    const int*   ei   = (const int*)  d_in[1];
    const float* ew   = (const float*)d_in[2];
    const float* encW = (const float*)d_in[3];
    const float* encB = (const float*)d_in[4];
    const float* Wl   = (const float*)d_in[5];
    const float* bl   = (const float*)d_in[6];
    const float* Wr   = (const float*)d_in[7];
    const float* br   = (const float*)d_in[8];
    const float* We   = (const float*)d_in[9];
    const float* att  = (const float*)d_in[10];
    const float* bias = (const float*)d_in[11];
    const float* lng  = (const float*)d_in[12];
    const float* lnb  = (const float*)d_in[13];
    const float* lnfg = (const float*)d_in[14];
    const float* lnfb = (const float*)d_in[15];
    const float* fcW  = (const float*)d_in[16];
    const float* fcb  = (const float*)d_in[17];
    float* out = (float*)d_out;

    const int* src = ei;
    const int* dst = ei + EE;

    char* ws = (char*)d_ws;
    size_t off = 0;
    auto alloc = [&](size_t bytes) -> void* {
        void* p = ws + off;
        off += (bytes + 255) & ~(size_t)255;
        return p;
    };
    float* h      = (float*)alloc((size_t)NN * HID * 4);
    unsigned short* xl_h  = (unsigned short*)alloc((size_t)NN * HID * 2 + 256);
    unsigned short* xr_h  = (unsigned short*)alloc((size_t)NN * HID * 2 + 256);
    unsigned short* hn    = (unsigned short*)alloc((size_t)NN * HID * 2 + 256);
    unsigned short* wf    = (unsigned short*)alloc((size_t)WPREP_L * 2);
    unsigned short* we    = (unsigned short*)alloc(12288 * 2);
    int*   deg    = (int*)  alloc((size_t)NN * 4);
    int*   rowptr = (int*)  alloc((size_t)(NN + 1) * 4);
    int*   cursor = (int*)  alloc((size_t)NN * 4);
    unsigned* epack = (unsigned*)alloc((size_t)EE * 4);
    uint2* ibuf   = (uint2*)alloc((size_t)NBUCK * BCAP * 8);
    int*   gcur   = (int*)  alloc(NBUCK * 4);
    int*   parts  = (int*)  alloc(256 * 4);

    const int NB = (NN + CHUNK - 1) / CHUNK;       // 49
    const int PB = (EE + PH1E - 1) / PH1E;         // 196
    const int MB = (NN + 63) / 64;                 // 782
    const int WB = (NN + 3) / 4;                   // 12500

    // CSR build (hist fused into binscatter)
    hipMemsetAsync(deg, 0, (size_t)NN * 4, stream);
    hipMemsetAsync(gcur, 0, NBUCK * 4, stream);
    k_binscatter<<<PB, 256, 0, stream>>>(src, dst, ew, deg, gcur, ibuf, EE);
    k_scan1<<<NB, 256, 0, stream>>>(deg, parts, NN);
    k_scan_mid<<<1, 64, 0, stream>>>(parts, NB, rowptr, NN);
    k_scan3<<<NB, 256, 0, stream>>>(deg, parts, rowptr, cursor, NN);
    k_binplace<<<NBUCK, 256, 0, stream>>>(ibuf, gcur, rowptr, epack, NN);

    // weight prep (fp16)
    k_wprep_all<<<(WPREP_TOT + 255) / 256, 256, 0, stream>>>(Wl, Wr, encW, wf, we);

    // encoder (+fused first LN)
    k_enc_mfma<<<MB, 256, 0, stream>>>(x, we, encB, lng, lnb, h, hn, NN);

    for (int l = 0; l < NL; l++) {
        k_gemm2_mfma<<<MB, 256, 0, stream>>>(hn,
            wf + (size_t)l * 2 * 9216,
            bl + l * HID, br + l * HID, xl_h, xr_h, NN);
        if (l < NL - 1) {
            k_gat_fused<<<WB, 256, 0, stream>>>(xl_h, xr_h, epack, rowptr,
                We + l * HID, att + l * HID, bias + l * HID,
                h, hn, (float*)nullptr,
                lng + (l + 1) * HID, lnb + (l + 1) * HID,
                (const float*)nullptr, (const float*)nullptr, 0, NN);
        } else {
            k_gat_fused<<<WB, 256, 0, stream>>>(xl_h, xr_h, epack, rowptr,
                We + l * HID, att + l * HID, bias + l * HID,
                h, (unsigned short*)nullptr, out,
                lnfg, lnfb, fcW, fcb, 1, NN);
        }
    }
}